// Round 2
// baseline (6794.648 us; speedup 1.0000x reference)
//
#include <hip/hip_runtime.h>
#include <hip/hip_bf16.h>
#include <math.h>

#define DEV __device__ __forceinline__

// ---------------- problem constants ----------------
constexpr int N_CONST = 8192;
constexpr int E_CONST = 131072;

constexpr float SQ3F     = 1.7320508075688772f;
constexpr float INV_SQ3F = 0.57735026918962576f;
constexpr float FAN_TP   = 0.20412414523193150f;   // 24^-0.5
constexpr float FAN_TP_V = 0.35355339059327373f;   // sqrt(3)*24^-0.5
constexpr float FAN_DOT  = 0.11180339887498949f;   // 80^-0.5
constexpr float INV16SQ  = 0.25f;                  // 16^-0.5
constexpr float INV8SQ   = 0.35355339059327373f;   // 8^-0.5
constexpr float HID_SC   = 0.125f;                 // 64^-0.5

// ---------------- workspace layout (float offsets) ----------------
enum : int {
  OFF_LIN0 = 0,
  OFF_LIN1 = OFF_LIN0 + 256,
  OFF_HQ0  = OFF_LIN1 + 64,
  OFF_HQ1  = OFF_HQ0 + 256,
  OFF_FCK1 = OFF_HQ1 + 64,
  OFF_FCK2 = OFF_FCK1 + 2048,
  OFF_FCV1 = OFF_FCK2 + 36864,
  OFF_FCV2 = OFF_FCV1 + 2048,
  OFF_DOT0 = OFF_FCV2 + 73728,
  OFF_DOT1 = OFF_DOT0 + 128,
  OFF_RB0  = OFF_DOT1 + 32,
  OFF_RB1  = OFF_RB0 + 128,
  OFF_RE0  = OFF_RB1 + 32,
  OFF_RE1  = OFF_RE0 + 128,
  OFF_F    = OFF_RE1 + 32,
  OFF_POS  = OFF_F + N_CONST * 40,
  OFF_X    = OFF_POS + N_CONST * 3,
  OFF_Q    = OFF_X + N_CONST * 40,
  OFF_MX   = OFF_Q + N_CONST * 20,
  OFF_Z    = OFF_MX + N_CONST,
  OFF_AGG  = OFF_Z + N_CONST,
  OFF_LOGIT= OFF_AGG + N_CONST * 40,
  OFF_CUT  = OFF_LOGIT + E_CONST,
  OFF_EX   = OFF_CUT + E_CONST,
  OFF_FLAG = OFF_EX + E_CONST,   // int flag stored in a float slot
};

// ---------------- dtype detection ----------------
__global__ void k_detect(const unsigned int* __restrict__ words, int* __restrict__ flag) {
  if (blockIdx.x != 0 || threadIdx.x != 0) return;
  int cnt = 0;
  for (int i = 0; i < 512; ++i) {
    unsigned b = (words[i] >> 8) & 0x7Fu;
    cnt += (b >= 0x3Au && b <= 0x43u) ? 1 : 0;
  }
  *flag = (cnt > 256) ? 1 : 0;
}

// ---------------- convert all float inputs to f32 in ws ----------------
struct CvtArgs {
  const void* src[16];
  int n[16];
  int off[16];
};

template <bool BF>
__global__ void k_cvt(CvtArgs a, float* __restrict__ ws, const int* __restrict__ flag) {
  if ((*flag != 0) != BF) return;
  int tid = blockIdx.x * blockDim.x + threadIdx.x;
  int stride = gridDim.x * blockDim.x;
  for (int arr = 0; arr < 16; ++arr) {
    float* dst = ws + a.off[arr];
    int n = a.n[arr];
    if (BF) {
      const __hip_bfloat16* s = (const __hip_bfloat16*)a.src[arr];
      for (int i = tid; i < n; i += stride) dst[i] = __bfloat162float(s[i]);
    } else {
      const float* s = (const float*)a.src[arr];
      for (int i = tid; i < n; i += stride) dst[i] = s[i];
    }
  }
}

// ---------------- helpers ----------------
DEV void atomicMaxF(float* addr, float val) {
  unsigned int* ai = (unsigned int*)addr;
  unsigned int old = *ai;
  while (__uint_as_float(old) < val) {
    unsigned int assumed = old;
    old = atomicCAS(ai, assumed, __float_as_uint(val));
    if (old == assumed) break;
  }
}

DEV float red4(float v) {
  v += __shfl_xor(v, 1);
  v += __shfl_xor(v, 2);
  return v;
}

// e3nn o3.Linear on 16x0e+8x1o input -> MO0 x0e + MO1 x1o
template <int MO0, int MO1>
DEV void lin_apply(const float* __restrict__ in40, const float* __restrict__ W0,
                   const float* __restrict__ W1, float* __restrict__ out) {
#pragma unroll
  for (int j = 0; j < MO0; ++j) {
    float a = 0.f;
#pragma unroll
    for (int i = 0; i < 16; ++i) a += in40[i] * W0[i * MO0 + j];
    out[j] = a * INV16SQ;
  }
#pragma unroll
  for (int w = 0; w < MO1; ++w) {
    float a0 = 0.f, a1 = 0.f, a2 = 0.f;
#pragma unroll
    for (int u = 0; u < 8; ++u) {
      float wt = W1[u * MO1 + w];
      a0 += in40[16 + u * 3 + 0] * wt;
      a1 += in40[16 + u * 3 + 1] * wt;
      a2 += in40[16 + u * 3 + 2] * wt;
    }
    out[MO0 + w * 3 + 0] = a0 * INV8SQ;
    out[MO0 + w * 3 + 1] = a1 * INV8SQ;
    out[MO0 + w * 3 + 2] = a2 * INV8SQ;
  }
}

DEV void edge_emb(float d, float emb[16]) {
#pragma unroll
  for (int i = 0; i < 16; ++i) {
    float c = (2.0f * (i + 1)) / 17.0f;
    float df = (d - c) * (17.0f * 0.5f);
    emb[i] = __expf(-df * df) * (4.0f / 1.12f);
  }
}

// hidden slice: this lane computes h for k in [g*16, g*16+16)
DEV void radial_hidden16(const float* __restrict__ W1, const float emb[16],
                         int g, float h[16]) {
#pragma unroll 1
  for (int i = 0; i < 16; ++i) {
    int k = g * 16 + i;
    float a = 0.f;
#pragma unroll
    for (int j = 0; j < 16; ++j) a += emb[j] * W1[j * 64 + k];
    a *= INV16SQ;
    float sig = 1.0f / (1.0f + __expf(-a));
    h[i] = a * sig * HID_SC;
  }
}

// shared per-edge prologue: geometry + features of source node
struct EdgeCtx {
  float y1[3], d;
  float fs[16];
  float fv[8][3];
  float vy[8];
};

DEV void edge_prologue(const float* __restrict__ pos, const float* __restrict__ x,
                       int s, int t, EdgeCtx& c) {
  float vx = pos[s * 3 + 0] - pos[t * 3 + 0];
  float vyy = pos[s * 3 + 1] - pos[t * 3 + 1];
  float vz = pos[s * 3 + 2] - pos[t * 3 + 2];
  c.d = sqrtf(vx * vx + vyy * vyy + vz * vz + 1e-24f);
  float inv = SQ3F / c.d;
  c.y1[0] = vx * inv; c.y1[1] = vyy * inv; c.y1[2] = vz * inv;

  const float* xs = x + s * 40;
#pragma unroll
  for (int i = 0; i < 16; ++i) c.fs[i] = xs[i];
#pragma unroll
  for (int u = 0; u < 8; ++u) {
    c.fv[u][0] = xs[16 + u * 3 + 0];
    c.fv[u][1] = xs[16 + u * 3 + 1];
    c.fv[u][2] = xs[16 + u * 3 + 2];
  }
#pragma unroll
  for (int u = 0; u < 8; ++u)
    c.vy[u] = (c.fv[u][0] * c.y1[0] + c.fv[u][1] * c.y1[1] + c.fv[u][2] * c.y1[2]) * INV_SQ3F;
}

// ---------------- node kernels ----------------
__global__ void k_lin_in(const float* __restrict__ f, const float* __restrict__ W0,
                         const float* __restrict__ W1, float* __restrict__ x, int N) {
  int n = blockIdx.x * blockDim.x + threadIdx.x;
  if (n >= N) return;
  lin_apply<16, 8>(f + n * 40, W0, W1, x + n * 40);
}

__global__ void k_q(const float* __restrict__ x, const float* __restrict__ W0,
                    const float* __restrict__ W1, float* __restrict__ q, int N) {
  int n = blockIdx.x * blockDim.x + threadIdx.x;
  if (n >= N) return;
  lin_apply<8, 4>(x + n * 40, W0, W1, q + n * 20);
}

__global__ void k_init(float* __restrict__ mx, float* __restrict__ z,
                       float* __restrict__ agg, int N) {
  int i = blockIdx.x * blockDim.x + threadIdx.x;
  if (i < N * 40) agg[i] = 0.f;
  if (i < N) { mx[i] = -INFINITY; z[i] = 0.f; }
}

__global__ void k_update(float* __restrict__ x, const float* __restrict__ agg, int n) {
  int i = blockIdx.x * blockDim.x + threadIdx.x;
  if (i < n) x[i] += agg[i];
}

// ---------------- edge kernel 1: K path + logits (4 lanes/edge) ----------------
__global__ void k_edge_k(const float* __restrict__ pos, const float* __restrict__ x,
                         const float* __restrict__ q,
                         const float* __restrict__ fck1, const float* __restrict__ fck2,
                         const float* __restrict__ dot0, const float* __restrict__ dot1,
                         const int* __restrict__ srcv, const int* __restrict__ dstv,
                         float* __restrict__ logit, float* __restrict__ cutb,
                         float* __restrict__ mx, int E) {
  int tid = blockIdx.x * blockDim.x + threadIdx.x;
  int e = tid >> 2;
  int g = tid & 3;
  if (e >= E) return;
  int s = srcv[e], t = dstv[e];

  EdgeCtx c;
  edge_prologue(pos, x, s, t, c);
  float emb[16];
  edge_emb(c.d, emb);
  float uu = 10.0f * (1.0f - 0.5f * c.d);
  float cut = (uu > 0.f) ? __expf(-1.0f / fmaxf(uu, 1e-9f)) : 0.f;

  float h[16];
  radial_hidden16(fck1, emb, g, h);

  float ks[8] = {0}, a2[4] = {0}, a3[4][3] = {{0}};
#pragma unroll 1
  for (int i = 0; i < 16; ++i) {
    float hk = h[i];
    const float* r = fck2 + (g * 16 + i) * 288;
#pragma unroll
    for (int u = 0; u < 16; ++u) {           // W1: 0e x 0e -> 0e
      float fu = hk * c.fs[u];
#pragma unroll
      for (int w = 0; w < 8; ++w) ks[w] += fu * r[u * 8 + w];
    }
#pragma unroll
    for (int u = 0; u < 16; ++u) {           // W2: 0e x 1o -> 1o (y1 separable)
      float fu = hk * c.fs[u];
#pragma unroll
      for (int w = 0; w < 4; ++w) a2[w] += fu * r[128 + u * 4 + w];
    }
#pragma unroll
    for (int u = 0; u < 8; ++u) {            // W3: 1o x 0e -> 1o
      float c0 = hk * c.fv[u][0], c1 = hk * c.fv[u][1], c2 = hk * c.fv[u][2];
#pragma unroll
      for (int w = 0; w < 4; ++w) {
        float wt = r[192 + u * 4 + w];
        a3[w][0] += c0 * wt; a3[w][1] += c1 * wt; a3[w][2] += c2 * wt;
      }
    }
#pragma unroll
    for (int u = 0; u < 8; ++u) {            // W4: 1o x 1o -> 0e
      float vu = hk * c.vy[u];
#pragma unroll
      for (int w = 0; w < 8; ++w) ks[w] += vu * r[224 + u * 8 + w];
    }
  }

  // cross-lane reduce over the 4 k-slices (butterfly: all lanes get full sums)
#pragma unroll
  for (int w = 0; w < 8; ++w) ks[w] = red4(ks[w]);
#pragma unroll
  for (int w = 0; w < 4; ++w) a2[w] = red4(a2[w]);
#pragma unroll
  for (int w = 0; w < 4; ++w)
#pragma unroll
    for (int i = 0; i < 3; ++i) a3[w][i] = red4(a3[w][i]);

  float kvf[4][3];
#pragma unroll
  for (int v = 0; v < 4; ++v)
#pragma unroll
    for (int i = 0; i < 3; ++i)
      kvf[v][i] = a2[v] * c.y1[i] * FAN_TP + a3[v][i] * FAN_TP_V;

  const float* qd = q + t * 20;
  float lg = 0.f;
#pragma unroll
  for (int u = 0; u < 8; ++u) {
    float qu = qd[u] * FAN_TP;
#pragma unroll
    for (int v = 0; v < 8; ++v) lg += qu * ks[v] * dot0[u * 8 + v];
  }
#pragma unroll
  for (int u = 0; u < 4; ++u) {
    float q0 = qd[8 + u * 3 + 0], q1 = qd[8 + u * 3 + 1], q2 = qd[8 + u * 3 + 2];
#pragma unroll
    for (int v = 0; v < 4; ++v) {
      float wt = dot1[u * 4 + v] * INV_SQ3F;
      lg += (q0 * kvf[v][0] + q1 * kvf[v][1] + q2 * kvf[v][2]) * wt;
    }
  }
  lg *= FAN_DOT;

  if (g == 0) {
    logit[e] = lg;
    cutb[e] = cut;
    atomicMaxF(&mx[t], lg);
  }
}

// ---------------- edge kernel 2: exp + denominator ----------------
__global__ void k_edge_ex(const int* __restrict__ dstv, const float* __restrict__ logit,
                          const float* __restrict__ cutb, const float* __restrict__ mx,
                          float* __restrict__ ex, float* __restrict__ z, int E) {
  int e = blockIdx.x * blockDim.x + threadIdx.x;
  if (e >= E) return;
  int t = dstv[e];
  float m = mx[t];
  if (m == -INFINITY) m = 0.f;
  float v = cutb[e] * __expf(logit[e] - m);
  ex[e] = v;
  atomicAdd(&z[t], v);
}

// ---------------- edge kernel 3: V path + scatter (4 lanes/edge) ----------------
__global__ void k_edge_v(const float* __restrict__ pos, const float* __restrict__ x,
                         const float* __restrict__ fcv1, const float* __restrict__ fcv2,
                         const int* __restrict__ srcv, const int* __restrict__ dstv,
                         const float* __restrict__ ex, const float* __restrict__ z,
                         float* __restrict__ agg, int E) {
  int tid = blockIdx.x * blockDim.x + threadIdx.x;
  int e = tid >> 2;
  int g = tid & 3;
  if (e >= E) return;
  int s = srcv[e], t = dstv[e];

  EdgeCtx c;
  edge_prologue(pos, x, s, t, c);
  float emb[16];
  edge_emb(c.d, emb);

  float h[16];
  radial_hidden16(fcv1, emb, g, h);

  float vs[16] = {0}, b2[8] = {0}, b3[8][3] = {{0}};
#pragma unroll 1
  for (int i = 0; i < 16; ++i) {
    float hk = h[i];
    const float* r = fcv2 + (g * 16 + i) * 576;
#pragma unroll
    for (int u = 0; u < 16; ++u) {           // W1: 16x16
      float fu = hk * c.fs[u];
#pragma unroll
      for (int w = 0; w < 16; ++w) vs[w] += fu * r[u * 16 + w];
    }
#pragma unroll
    for (int u = 0; u < 16; ++u) {           // W2: 16x8
      float fu = hk * c.fs[u];
#pragma unroll
      for (int w = 0; w < 8; ++w) b2[w] += fu * r[256 + u * 8 + w];
    }
#pragma unroll
    for (int u = 0; u < 8; ++u) {            // W3: 8x8
      float c0 = hk * c.fv[u][0], c1 = hk * c.fv[u][1], c2 = hk * c.fv[u][2];
#pragma unroll
      for (int w = 0; w < 8; ++w) {
        float wt = r[384 + u * 8 + w];
        b3[w][0] += c0 * wt; b3[w][1] += c1 * wt; b3[w][2] += c2 * wt;
      }
    }
#pragma unroll
    for (int u = 0; u < 8; ++u) {            // W4: 8x16
      float vu = hk * c.vy[u];
#pragma unroll
      for (int w = 0; w < 16; ++w) vs[w] += vu * r[448 + u * 16 + w];
    }
  }

  // cross-lane reduce over the 4 k-slices
#pragma unroll
  for (int w = 0; w < 16; ++w) vs[w] = red4(vs[w]);
#pragma unroll
  for (int w = 0; w < 8; ++w) b2[w] = red4(b2[w]);
#pragma unroll
  for (int w = 0; w < 8; ++w)
#pragma unroll
    for (int i = 0; i < 3; ++i) b3[w][i] = red4(b3[w][i]);

  float zz = z[t];
  zz = (zz == 0.f) ? 1.f : zz;
  float alpha = ex[e] / zz;
  float wgt = sqrtf(alpha + 1e-12f);

  float* at = agg + t * 40;
  // distribute the 40 atomics across the 4 lanes of the group
#pragma unroll
  for (int w = 0; w < 16; ++w)
    if ((w & 3) == g) atomicAdd(&at[w], wgt * vs[w] * FAN_TP);
#pragma unroll
  for (int w = 0; w < 8; ++w) {
#pragma unroll
    for (int i = 0; i < 3; ++i) {
      int idx = w * 3 + i;
      if ((idx & 3) == g) {
        float v = b2[w] * c.y1[i] * FAN_TP + b3[w][i] * FAN_TP_V;
        atomicAdd(&at[16 + idx], wgt * v);
      }
    }
  }
}

// ---------------- output kernel ----------------
template <bool BF>
__global__ void k_out(const float* __restrict__ x, const float* __restrict__ rb0,
                      const float* __restrict__ rb1, const float* __restrict__ re0,
                      const float* __restrict__ re1, void* __restrict__ out, int N,
                      const int* __restrict__ flag) {
  if ((*flag != 0) != BF) return;
  int n = blockIdx.x * blockDim.x + threadIdx.x;
  if (n >= N) return;
  float b[20], eta[20];
  lin_apply<8, 4>(x + n * 40, rb0, rb1, b);
  lin_apply<8, 4>(x + n * 40, re0, re1, eta);
  if (BF) {
    __hip_bfloat16* o = (__hip_bfloat16*)out;
#pragma unroll
    for (int j = 0; j < 20; ++j) o[n * 20 + j] = __float2bfloat16(b[j]);
#pragma unroll
    for (int j = 0; j < 20; ++j) o[N * 20 + n * 20 + j] = __float2bfloat16(eta[j]);
  } else {
    float* o = (float*)out;
#pragma unroll
    for (int j = 0; j < 20; ++j) o[n * 20 + j] = b[j];
#pragma unroll
    for (int j = 0; j < 20; ++j) o[N * 20 + n * 20 + j] = eta[j];
  }
}

// ---------------- host ----------------
extern "C" void kernel_launch(void* const* d_in, const int* in_sizes, int n_in,
                              void* d_out, int out_size, void* d_ws, size_t ws_size,
                              hipStream_t stream) {
  float* ws = (float*)d_ws;
  const int N = in_sizes[0] / 40;
  const int E = in_sizes[16];
  const int* src = (const int*)d_in[16];
  const int* dst = (const int*)d_in[17];
  int* flag = (int*)(ws + OFF_FLAG);

  k_detect<<<1, 64, 0, stream>>>((const unsigned int*)d_in[0], flag);

  CvtArgs ca;
  const int order[16] = {2, 3, 4, 5, 6, 7, 8, 9, 10, 11, 12, 13, 14, 15, 0, 1};
  const int offs[16] = {OFF_LIN0, OFF_LIN1, OFF_HQ0, OFF_HQ1, OFF_FCK1, OFF_FCK2,
                        OFF_FCV1, OFF_FCV2, OFF_DOT0, OFF_DOT1, OFF_RB0, OFF_RB1,
                        OFF_RE0, OFF_RE1, OFF_F, OFF_POS};
  for (int i = 0; i < 16; ++i) {
    ca.src[i] = d_in[order[i]];
    ca.n[i] = in_sizes[order[i]];
    ca.off[i] = offs[i];
  }
  k_cvt<false><<<512, 256, 0, stream>>>(ca, ws, flag);
  k_cvt<true><<<512, 256, 0, stream>>>(ca, ws, flag);

  float* x = ws + OFF_X;
  float* q = ws + OFF_Q;
  float* mx = ws + OFF_MX;
  float* z = ws + OFF_Z;
  float* agg = ws + OFF_AGG;
  float* logit = ws + OFF_LOGIT;
  float* cutb = ws + OFF_CUT;
  float* exb = ws + OFF_EX;
  const float* pos = ws + OFF_POS;

  const int nodeBlocks = (N + 255) / 256;
  const int vecBlocks = (N * 40 + 255) / 256;
  const int edgeBlocks = (E + 255) / 256;
  const int edgeBlocks4 = (E * 4 + 255) / 256;   // 4 lanes per edge

  k_lin_in<<<nodeBlocks, 256, 0, stream>>>(ws + OFF_F, ws + OFF_LIN0, ws + OFF_LIN1, x, N);

  for (int l = 0; l < 2; ++l) {
    k_init<<<vecBlocks, 256, 0, stream>>>(mx, z, agg, N);
    k_q<<<nodeBlocks, 256, 0, stream>>>(x, ws + OFF_HQ0 + l * 128, ws + OFF_HQ1 + l * 32, q, N);
    k_edge_k<<<edgeBlocks4, 256, 0, stream>>>(
        pos, x, q, ws + OFF_FCK1 + l * 1024, ws + OFF_FCK2 + l * 18432,
        ws + OFF_DOT0 + l * 64, ws + OFF_DOT1 + l * 16, src, dst, logit, cutb, mx, E);
    k_edge_ex<<<edgeBlocks, 256, 0, stream>>>(dst, logit, cutb, mx, exb, z, E);
    k_edge_v<<<edgeBlocks4, 256, 0, stream>>>(
        pos, x, ws + OFF_FCV1 + l * 1024, ws + OFF_FCV2 + l * 36864, src, dst, exb, z, agg, E);
    k_update<<<vecBlocks, 256, 0, stream>>>(x, agg, N * 40);
  }

  k_out<false><<<nodeBlocks, 256, 0, stream>>>(x, ws + OFF_RB0, ws + OFF_RB1,
                                               ws + OFF_RE0, ws + OFF_RE1, d_out, N, flag);
  k_out<true><<<nodeBlocks, 256, 0, stream>>>(x, ws + OFF_RB0, ws + OFF_RB1,
                                              ws + OFF_RE0, ws + OFF_RE1, d_out, N, flag);
}

// Round 3
// 948.092 us; speedup vs baseline: 7.1667x; 7.1667x over previous
//
#include <hip/hip_runtime.h>
#include <hip/hip_bf16.h>
#include <math.h>

#define DEV __device__ __forceinline__

// ---------------- problem constants ----------------
constexpr int N_CONST = 8192;
constexpr int E_CONST = 131072;

constexpr float SQ3F     = 1.7320508075688772f;
constexpr float INV_SQ3F = 0.57735026918962576f;
constexpr float FAN_TP   = 0.20412414523193150f;   // 24^-0.5
constexpr float FAN_TP_V = 0.35355339059327373f;   // sqrt(3)*24^-0.5
constexpr float FAN_DOT  = 0.11180339887498949f;   // 80^-0.5
constexpr float INV16SQ  = 0.25f;                  // 16^-0.5
constexpr float INV8SQ   = 0.35355339059327373f;   // 8^-0.5
constexpr float HID_SC   = 0.125f;                 // 64^-0.5

// ---------------- workspace layout (float offsets) ----------------
enum : int {
  OFF_LIN0 = 0,
  OFF_LIN1 = OFF_LIN0 + 256,
  OFF_HQ0  = OFF_LIN1 + 64,
  OFF_HQ1  = OFF_HQ0 + 256,
  OFF_FCK1 = OFF_HQ1 + 64,
  OFF_FCK2 = OFF_FCK1 + 2048,
  OFF_FCV1 = OFF_FCK2 + 36864,
  OFF_FCV2 = OFF_FCV1 + 2048,
  OFF_DOT0 = OFF_FCV2 + 73728,
  OFF_DOT1 = OFF_DOT0 + 128,
  OFF_RB0  = OFF_DOT1 + 32,
  OFF_RB1  = OFF_RB0 + 128,
  OFF_RE0  = OFF_RB1 + 32,
  OFF_RE1  = OFF_RE0 + 128,
  OFF_F    = OFF_RE1 + 32,
  OFF_POS  = OFF_F + N_CONST * 40,
  OFF_X    = OFF_POS + N_CONST * 3,
  OFF_Q    = OFF_X + N_CONST * 40,
  OFF_MX   = OFF_Q + N_CONST * 20,
  OFF_Z    = OFF_MX + N_CONST,
  OFF_AGG  = OFF_Z + N_CONST,
  OFF_LOGIT= OFF_AGG + N_CONST * 40,
  OFF_CUT  = OFF_LOGIT + E_CONST,
  OFF_EX   = OFF_CUT + E_CONST,
  OFF_FLAG = OFF_EX + E_CONST,   // int flag stored in a float slot
};

// ---------------- dtype detection ----------------
__global__ void k_detect(const unsigned int* __restrict__ words, int* __restrict__ flag) {
  if (blockIdx.x != 0 || threadIdx.x != 0) return;
  int cnt = 0;
  for (int i = 0; i < 512; ++i) {
    unsigned b = (words[i] >> 8) & 0x7Fu;
    cnt += (b >= 0x3Au && b <= 0x43u) ? 1 : 0;
  }
  *flag = (cnt > 256) ? 1 : 0;
}

// ---------------- convert all float inputs to f32 in ws ----------------
struct CvtArgs {
  const void* src[16];
  int n[16];
  int off[16];
};

template <bool BF>
__global__ void k_cvt(CvtArgs a, float* __restrict__ ws, const int* __restrict__ flag) {
  if ((*flag != 0) != BF) return;
  int tid = blockIdx.x * blockDim.x + threadIdx.x;
  int stride = gridDim.x * blockDim.x;
  for (int arr = 0; arr < 16; ++arr) {
    float* dst = ws + a.off[arr];
    int n = a.n[arr];
    if (BF) {
      const __hip_bfloat16* s = (const __hip_bfloat16*)a.src[arr];
      for (int i = tid; i < n; i += stride) dst[i] = __bfloat162float(s[i]);
    } else {
      const float* s = (const float*)a.src[arr];
      for (int i = tid; i < n; i += stride) dst[i] = s[i];
    }
  }
}

// ---------------- helpers ----------------
DEV void atomicMaxF(float* addr, float val) {
  unsigned int* ai = (unsigned int*)addr;
  unsigned int old = *ai;
  while (__uint_as_float(old) < val) {
    unsigned int assumed = old;
    old = atomicCAS(ai, assumed, __float_as_uint(val));
    if (old == assumed) break;
  }
}

// e3nn o3.Linear on 16x0e+8x1o input -> MO0 x0e + MO1 x1o
template <int MO0, int MO1>
DEV void lin_apply(const float* __restrict__ in40, const float* __restrict__ W0,
                   const float* __restrict__ W1, float* __restrict__ out) {
#pragma unroll
  for (int j = 0; j < MO0; ++j) {
    float a = 0.f;
#pragma unroll
    for (int i = 0; i < 16; ++i) a += in40[i] * W0[i * MO0 + j];
    out[j] = a * INV16SQ;
  }
#pragma unroll
  for (int w = 0; w < MO1; ++w) {
    float a0 = 0.f, a1 = 0.f, a2 = 0.f;
#pragma unroll
    for (int u = 0; u < 8; ++u) {
      float wt = W1[u * MO1 + w];
      a0 += in40[16 + u * 3 + 0] * wt;
      a1 += in40[16 + u * 3 + 1] * wt;
      a2 += in40[16 + u * 3 + 2] * wt;
    }
    out[MO0 + w * 3 + 0] = a0 * INV8SQ;
    out[MO0 + w * 3 + 1] = a1 * INV8SQ;
    out[MO0 + w * 3 + 2] = a2 * INV8SQ;
  }
}

DEV void edge_emb(float d, float emb[16]) {
#pragma unroll
  for (int i = 0; i < 16; ++i) {
    float c = (2.0f * (i + 1)) / 17.0f;
    float df = (d - c) * (17.0f * 0.5f);
    emb[i] = __expf(-df * df) * (4.0f / 1.12f);
  }
}

// hidden slice: this WAVE computes h for k in [wv*16, wv*16+16); wv is wave-uniform
DEV void radial_hidden16(const float* __restrict__ W1, const float emb[16],
                         int wv, float h[16]) {
#pragma unroll 1
  for (int i = 0; i < 16; ++i) {
    float a = 0.f;
#pragma unroll
    for (int j = 0; j < 16; ++j) a += emb[j] * W1[j * 64 + wv * 16 + i];
    a *= INV16SQ;
    float sig = 1.0f / (1.0f + __expf(-a));
    h[i] = a * sig * HID_SC;
  }
}

// shared per-edge prologue: geometry + features of source node
struct EdgeCtx {
  float y1[3], d;
  float fs[16];
  float fv[8][3];
  float vy[8];
};

DEV void edge_prologue(const float* __restrict__ pos, const float* __restrict__ x,
                       int s, int t, EdgeCtx& c) {
  float vx = pos[s * 3 + 0] - pos[t * 3 + 0];
  float vyy = pos[s * 3 + 1] - pos[t * 3 + 1];
  float vz = pos[s * 3 + 2] - pos[t * 3 + 2];
  c.d = sqrtf(vx * vx + vyy * vyy + vz * vz + 1e-24f);
  float inv = SQ3F / c.d;
  c.y1[0] = vx * inv; c.y1[1] = vyy * inv; c.y1[2] = vz * inv;

  const float* xs = x + s * 40;
#pragma unroll
  for (int i = 0; i < 16; ++i) c.fs[i] = xs[i];
#pragma unroll
  for (int u = 0; u < 8; ++u) {
    c.fv[u][0] = xs[16 + u * 3 + 0];
    c.fv[u][1] = xs[16 + u * 3 + 1];
    c.fv[u][2] = xs[16 + u * 3 + 2];
  }
#pragma unroll
  for (int u = 0; u < 8; ++u)
    c.vy[u] = (c.fv[u][0] * c.y1[0] + c.fv[u][1] * c.y1[1] + c.fv[u][2] * c.y1[2]) * INV_SQ3F;
}

// ---------------- node kernels ----------------
__global__ void k_lin_in(const float* __restrict__ f, const float* __restrict__ W0,
                         const float* __restrict__ W1, float* __restrict__ x, int N) {
  int n = blockIdx.x * blockDim.x + threadIdx.x;
  if (n >= N) return;
  lin_apply<16, 8>(f + n * 40, W0, W1, x + n * 40);
}

__global__ void k_q(const float* __restrict__ x, const float* __restrict__ W0,
                    const float* __restrict__ W1, float* __restrict__ q, int N) {
  int n = blockIdx.x * blockDim.x + threadIdx.x;
  if (n >= N) return;
  lin_apply<8, 4>(x + n * 40, W0, W1, q + n * 20);
}

__global__ void k_init(float* __restrict__ mx, float* __restrict__ z,
                       float* __restrict__ agg, int N) {
  int i = blockIdx.x * blockDim.x + threadIdx.x;
  if (i < N * 40) agg[i] = 0.f;
  if (i < N) { mx[i] = -INFINITY; z[i] = 0.f; }
}

__global__ void k_update(float* __restrict__ x, const float* __restrict__ agg, int n) {
  int i = blockIdx.x * blockDim.x + threadIdx.x;
  if (i < n) x[i] += agg[i];
}

// ---------------- edge kernel 1: K path + logits ----------------
// block = 256 threads = 4 waves; block owns 64 edges (one per lane);
// wave wv owns k in [wv*16, wv*16+16) -> weight addresses stay wave-uniform
// (scalar loads). Partials summed across waves via LDS f32 atomics.
__global__ void __launch_bounds__(256)
k_edge_k(const float* __restrict__ pos, const float* __restrict__ x,
         const float* __restrict__ q,
         const float* __restrict__ fck1, const float* __restrict__ fck2,
         const float* __restrict__ dot0, const float* __restrict__ dot1,
         const int* __restrict__ srcv, const int* __restrict__ dstv,
         float* __restrict__ logit, float* __restrict__ cutb,
         float* __restrict__ mx, int E) {
  __shared__ float acc[64 * 25];   // [edge][0:8 ks | 8:12 a2 | 12:24 a3], stride 25
  __shared__ float y1s[64 * 3];

  const int tid = threadIdx.x;
  const int wv = __builtin_amdgcn_readfirstlane(tid >> 6);
  const int lane = tid & 63;
  const int e0 = blockIdx.x * 64;
  const int e = e0 + lane;
  const bool valid = e < E;

  for (int i = tid; i < 64 * 25; i += 256) acc[i] = 0.f;
  __syncthreads();

  int s = valid ? srcv[e] : 0, t = valid ? dstv[e] : 0;
  EdgeCtx c;
  edge_prologue(pos, x, s, t, c);
  float emb[16];
  edge_emb(c.d, emb);

  if (wv == 0 && valid) {
    float uu = 10.0f * (1.0f - 0.5f * c.d);
    cutb[e] = (uu > 0.f) ? __expf(-1.0f / fmaxf(uu, 1e-9f)) : 0.f;
    y1s[lane * 3 + 0] = c.y1[0];
    y1s[lane * 3 + 1] = c.y1[1];
    y1s[lane * 3 + 2] = c.y1[2];
  }

  float h[16];
  radial_hidden16(fck1, emb, wv, h);

  float ks[8] = {0}, a2[4] = {0}, a3[4][3] = {{0}};
#pragma unroll 1
  for (int i = 0; i < 16; ++i) {
    float hk = h[i];
    const float* r = fck2 + (wv * 16 + i) * 288;
#pragma unroll
    for (int u = 0; u < 16; ++u) {           // W1: 0e x 0e -> 0e
      float fu = hk * c.fs[u];
#pragma unroll
      for (int w = 0; w < 8; ++w) ks[w] += fu * r[u * 8 + w];
    }
#pragma unroll
    for (int u = 0; u < 16; ++u) {           // W2: 0e x 1o -> 1o (y1 separable)
      float fu = hk * c.fs[u];
#pragma unroll
      for (int w = 0; w < 4; ++w) a2[w] += fu * r[128 + u * 4 + w];
    }
#pragma unroll
    for (int u = 0; u < 8; ++u) {            // W3: 1o x 0e -> 1o
      float c0 = hk * c.fv[u][0], c1 = hk * c.fv[u][1], c2 = hk * c.fv[u][2];
#pragma unroll
      for (int w = 0; w < 4; ++w) {
        float wt = r[192 + u * 4 + w];
        a3[w][0] += c0 * wt; a3[w][1] += c1 * wt; a3[w][2] += c2 * wt;
      }
    }
#pragma unroll
    for (int u = 0; u < 8; ++u) {            // W4: 1o x 1o -> 0e
      float vu = hk * c.vy[u];
#pragma unroll
      for (int w = 0; w < 8; ++w) ks[w] += vu * r[224 + u * 8 + w];
    }
  }

  if (valid) {
    float* a = acc + lane * 25;
#pragma unroll
    for (int w = 0; w < 8; ++w) atomicAdd(&a[w], ks[w]);
#pragma unroll
    for (int w = 0; w < 4; ++w) atomicAdd(&a[8 + w], a2[w]);
#pragma unroll
    for (int w = 0; w < 4; ++w)
#pragma unroll
      for (int i = 0; i < 3; ++i) atomicAdd(&a[12 + w * 3 + i], a3[w][i]);
  }
  __syncthreads();

  // epilogue: one thread per edge
  if (tid < 64) {
    int ee = e0 + tid;
    if (ee < E) {
      int tt = dstv[ee];
      const float* a = acc + tid * 25;
      float yy0 = y1s[tid * 3 + 0], yy1 = y1s[tid * 3 + 1], yy2 = y1s[tid * 3 + 2];
      const float* qd = q + tt * 20;
      float lg = 0.f;
#pragma unroll
      for (int u = 0; u < 8; ++u) {
        float qu = qd[u] * FAN_TP;
#pragma unroll
        for (int v = 0; v < 8; ++v) lg += qu * a[v] * dot0[u * 8 + v];
      }
#pragma unroll
      for (int v = 0; v < 4; ++v) {
        float k0 = a[8 + v] * yy0 * FAN_TP + a[12 + v * 3 + 0] * FAN_TP_V;
        float k1 = a[8 + v] * yy1 * FAN_TP + a[12 + v * 3 + 1] * FAN_TP_V;
        float k2 = a[8 + v] * yy2 * FAN_TP + a[12 + v * 3 + 2] * FAN_TP_V;
#pragma unroll
        for (int u = 0; u < 4; ++u) {
          float wt = dot1[u * 4 + v] * INV_SQ3F;
          lg += (qd[8 + u * 3 + 0] * k0 + qd[8 + u * 3 + 1] * k1 +
                 qd[8 + u * 3 + 2] * k2) * wt;
        }
      }
      lg *= FAN_DOT;
      logit[ee] = lg;
      atomicMaxF(&mx[tt], lg);
    }
  }
}

// ---------------- edge kernel 2: exp + denominator ----------------
__global__ void k_edge_ex(const int* __restrict__ dstv, const float* __restrict__ logit,
                          const float* __restrict__ cutb, const float* __restrict__ mx,
                          float* __restrict__ ex, float* __restrict__ z, int E) {
  int e = blockIdx.x * blockDim.x + threadIdx.x;
  if (e >= E) return;
  int t = dstv[e];
  float m = mx[t];
  if (m == -INFINITY) m = 0.f;
  float v = cutb[e] * __expf(logit[e] - m);
  ex[e] = v;
  atomicAdd(&z[t], v);
}

// ---------------- edge kernel 3: V path + scatter ----------------
__global__ void __launch_bounds__(256)
k_edge_v(const float* __restrict__ pos, const float* __restrict__ x,
         const float* __restrict__ fcv1, const float* __restrict__ fcv2,
         const int* __restrict__ srcv, const int* __restrict__ dstv,
         const float* __restrict__ ex, const float* __restrict__ z,
         float* __restrict__ agg, int E) {
  __shared__ float acc[64 * 49];   // [edge][0:16 vs | 16:24 b2 | 24:48 b3], stride 49
  __shared__ float y1s[64 * 3];

  const int tid = threadIdx.x;
  const int wv = __builtin_amdgcn_readfirstlane(tid >> 6);
  const int lane = tid & 63;
  const int e0 = blockIdx.x * 64;
  const int e = e0 + lane;
  const bool valid = e < E;

  for (int i = tid; i < 64 * 49; i += 256) acc[i] = 0.f;
  __syncthreads();

  int s = valid ? srcv[e] : 0, t = valid ? dstv[e] : 0;
  EdgeCtx c;
  edge_prologue(pos, x, s, t, c);
  float emb[16];
  edge_emb(c.d, emb);

  if (wv == 0 && valid) {
    y1s[lane * 3 + 0] = c.y1[0];
    y1s[lane * 3 + 1] = c.y1[1];
    y1s[lane * 3 + 2] = c.y1[2];
  }

  float h[16];
  radial_hidden16(fcv1, emb, wv, h);

  float vs[16] = {0}, b2[8] = {0}, b3[8][3] = {{0}};
#pragma unroll 1
  for (int i = 0; i < 16; ++i) {
    float hk = h[i];
    const float* r = fcv2 + (wv * 16 + i) * 576;
#pragma unroll
    for (int u = 0; u < 16; ++u) {           // W1: 16x16
      float fu = hk * c.fs[u];
#pragma unroll
      for (int w = 0; w < 16; ++w) vs[w] += fu * r[u * 16 + w];
    }
#pragma unroll
    for (int u = 0; u < 16; ++u) {           // W2: 16x8
      float fu = hk * c.fs[u];
#pragma unroll
      for (int w = 0; w < 8; ++w) b2[w] += fu * r[256 + u * 8 + w];
    }
#pragma unroll
    for (int u = 0; u < 8; ++u) {            // W3: 8x8
      float c0 = hk * c.fv[u][0], c1 = hk * c.fv[u][1], c2 = hk * c.fv[u][2];
#pragma unroll
      for (int w = 0; w < 8; ++w) {
        float wt = r[384 + u * 8 + w];
        b3[w][0] += c0 * wt; b3[w][1] += c1 * wt; b3[w][2] += c2 * wt;
      }
    }
#pragma unroll
    for (int u = 0; u < 8; ++u) {            // W4: 8x16
      float vu = hk * c.vy[u];
#pragma unroll
      for (int w = 0; w < 16; ++w) vs[w] += vu * r[448 + u * 16 + w];
    }
  }

  if (valid) {
    float* a = acc + lane * 49;
#pragma unroll
    for (int w = 0; w < 16; ++w) atomicAdd(&a[w], vs[w]);
#pragma unroll
    for (int w = 0; w < 8; ++w) atomicAdd(&a[16 + w], b2[w]);
#pragma unroll
    for (int w = 0; w < 8; ++w)
#pragma unroll
      for (int i = 0; i < 3; ++i) atomicAdd(&a[24 + w * 3 + i], b3[w][i]);
  }
  __syncthreads();

  // epilogue: 4 threads per edge, each owns outputs idx % 4 == p
  {
    int e_l = tid >> 2, p = tid & 3;
    int ee = e0 + e_l;
    if (ee < E) {
      int tt = dstv[ee];
      float zz = z[tt];
      zz = (zz == 0.f) ? 1.f : zz;
      float alpha = ex[ee] / zz;
      float wgt = sqrtf(alpha + 1e-12f);
      float yy0 = y1s[e_l * 3 + 0], yy1 = y1s[e_l * 3 + 1], yy2 = y1s[e_l * 3 + 2];
      const float* a = acc + e_l * 49;
      float* at = agg + tt * 40;
#pragma unroll
      for (int w = 0; w < 16; w += 4)
        atomicAdd(&at[w + p], wgt * a[w + p] * FAN_TP);
#pragma unroll
      for (int base = 0; base < 24; base += 4) {
        int idx = base + p;
        int w = idx / 3, i2 = idx - w * 3;
        float yi = (i2 == 0) ? yy0 : ((i2 == 1) ? yy1 : yy2);
        float v = a[16 + w] * yi * FAN_TP + a[24 + idx] * FAN_TP_V;
        atomicAdd(&at[16 + idx], wgt * v);
      }
    }
  }
}

// ---------------- output kernel ----------------
template <bool BF>
__global__ void k_out(const float* __restrict__ x, const float* __restrict__ rb0,
                      const float* __restrict__ rb1, const float* __restrict__ re0,
                      const float* __restrict__ re1, void* __restrict__ out, int N,
                      const int* __restrict__ flag) {
  if ((*flag != 0) != BF) return;
  int n = blockIdx.x * blockDim.x + threadIdx.x;
  if (n >= N) return;
  float b[20], eta[20];
  lin_apply<8, 4>(x + n * 40, rb0, rb1, b);
  lin_apply<8, 4>(x + n * 40, re0, re1, eta);
  if (BF) {
    __hip_bfloat16* o = (__hip_bfloat16*)out;
#pragma unroll
    for (int j = 0; j < 20; ++j) o[n * 20 + j] = __float2bfloat16(b[j]);
#pragma unroll
    for (int j = 0; j < 20; ++j) o[N * 20 + n * 20 + j] = __float2bfloat16(eta[j]);
  } else {
    float* o = (float*)out;
#pragma unroll
    for (int j = 0; j < 20; ++j) o[n * 20 + j] = b[j];
#pragma unroll
    for (int j = 0; j < 20; ++j) o[N * 20 + n * 20 + j] = eta[j];
  }
}

// ---------------- host ----------------
extern "C" void kernel_launch(void* const* d_in, const int* in_sizes, int n_in,
                              void* d_out, int out_size, void* d_ws, size_t ws_size,
                              hipStream_t stream) {
  float* ws = (float*)d_ws;
  const int N = in_sizes[0] / 40;
  const int E = in_sizes[16];
  const int* src = (const int*)d_in[16];
  const int* dst = (const int*)d_in[17];
  int* flag = (int*)(ws + OFF_FLAG);

  k_detect<<<1, 64, 0, stream>>>((const unsigned int*)d_in[0], flag);

  CvtArgs ca;
  const int order[16] = {2, 3, 4, 5, 6, 7, 8, 9, 10, 11, 12, 13, 14, 15, 0, 1};
  const int offs[16] = {OFF_LIN0, OFF_LIN1, OFF_HQ0, OFF_HQ1, OFF_FCK1, OFF_FCK2,
                        OFF_FCV1, OFF_FCV2, OFF_DOT0, OFF_DOT1, OFF_RB0, OFF_RB1,
                        OFF_RE0, OFF_RE1, OFF_F, OFF_POS};
  for (int i = 0; i < 16; ++i) {
    ca.src[i] = d_in[order[i]];
    ca.n[i] = in_sizes[order[i]];
    ca.off[i] = offs[i];
  }
  k_cvt<false><<<512, 256, 0, stream>>>(ca, ws, flag);
  k_cvt<true><<<512, 256, 0, stream>>>(ca, ws, flag);

  float* x = ws + OFF_X;
  float* q = ws + OFF_Q;
  float* mx = ws + OFF_MX;
  float* z = ws + OFF_Z;
  float* agg = ws + OFF_AGG;
  float* logit = ws + OFF_LOGIT;
  float* cutb = ws + OFF_CUT;
  float* exb = ws + OFF_EX;
  const float* pos = ws + OFF_POS;

  const int nodeBlocks = (N + 255) / 256;
  const int vecBlocks = (N * 40 + 255) / 256;
  const int edgeBlocks = (E + 255) / 256;
  const int eb64 = (E + 63) / 64;   // block = 64 edges x 4 k-slice waves

  k_lin_in<<<nodeBlocks, 256, 0, stream>>>(ws + OFF_F, ws + OFF_LIN0, ws + OFF_LIN1, x, N);

  for (int l = 0; l < 2; ++l) {
    k_init<<<vecBlocks, 256, 0, stream>>>(mx, z, agg, N);
    k_q<<<nodeBlocks, 256, 0, stream>>>(x, ws + OFF_HQ0 + l * 128, ws + OFF_HQ1 + l * 32, q, N);
    k_edge_k<<<eb64, 256, 0, stream>>>(
        pos, x, q, ws + OFF_FCK1 + l * 1024, ws + OFF_FCK2 + l * 18432,
        ws + OFF_DOT0 + l * 64, ws + OFF_DOT1 + l * 16, src, dst, logit, cutb, mx, E);
    k_edge_ex<<<edgeBlocks, 256, 0, stream>>>(dst, logit, cutb, mx, exb, z, E);
    k_edge_v<<<eb64, 256, 0, stream>>>(
        pos, x, ws + OFF_FCV1 + l * 1024, ws + OFF_FCV2 + l * 36864, src, dst, exb, z, agg, E);
    k_update<<<vecBlocks, 256, 0, stream>>>(x, agg, N * 40);
  }

  k_out<false><<<nodeBlocks, 256, 0, stream>>>(x, ws + OFF_RB0, ws + OFF_RB1,
                                               ws + OFF_RE0, ws + OFF_RE1, d_out, N, flag);
  k_out<true><<<nodeBlocks, 256, 0, stream>>>(x, ws + OFF_RB0, ws + OFF_RB1,
                                              ws + OFF_RE0, ws + OFF_RE1, d_out, N, flag);
}

// Round 4
// 749.394 us; speedup vs baseline: 9.0669x; 1.2651x over previous
//
#include <hip/hip_runtime.h>
#include <hip/hip_bf16.h>
#include <math.h>

#define DEV __device__ __forceinline__

typedef __attribute__((ext_vector_type(4))) float f32x4;
typedef __attribute__((ext_vector_type(8))) __bf16 bf16x8;

// ---------------- problem constants ----------------
constexpr int N_CONST = 8192;
constexpr int E_CONST = 131072;

constexpr float SQ3F     = 1.7320508075688772f;
constexpr float INV_SQ3F = 0.57735026918962576f;
constexpr float FAN_TP   = 0.20412414523193150f;   // 24^-0.5
constexpr float FAN_TP_V = 0.35355339059327373f;   // sqrt(3)*24^-0.5
constexpr float FAN_DOT  = 0.11180339887498949f;   // 80^-0.5
constexpr float INV16SQ  = 0.25f;                  // 16^-0.5
constexpr float INV8SQ   = 0.35355339059327373f;   // 8^-0.5
constexpr float HID_SC   = 0.125f;                 // 64^-0.5

// ---------------- workspace layout (float offsets) ----------------
enum : int {
  OFF_LIN0 = 0,
  OFF_LIN1 = OFF_LIN0 + 256,
  OFF_HQ0  = OFF_LIN1 + 64,
  OFF_HQ1  = OFF_HQ0 + 256,
  OFF_FCK1 = OFF_HQ1 + 64,
  OFF_FCK2 = OFF_FCK1 + 2048,
  OFF_FCV1 = OFF_FCK2 + 36864,
  OFF_FCV2 = OFF_FCV1 + 2048,
  OFF_DOT0 = OFF_FCV2 + 73728,
  OFF_DOT1 = OFF_DOT0 + 128,
  OFF_RB0  = OFF_DOT1 + 32,
  OFF_RB1  = OFF_RB0 + 128,
  OFF_RE0  = OFF_RB1 + 32,
  OFF_RE1  = OFF_RE0 + 128,
  OFF_F    = OFF_RE1 + 32,
  OFF_POS  = OFF_F + N_CONST * 40,
  OFF_X    = OFF_POS + N_CONST * 3,
  OFF_Q    = OFF_X + N_CONST * 40,
  OFF_MX   = OFF_Q + N_CONST * 20,
  OFF_Z    = OFF_MX + N_CONST,
  OFF_AGG  = OFF_Z + N_CONST,
  OFF_LOGIT= OFF_AGG + N_CONST * 40,
  OFF_CUT  = OFF_LOGIT + E_CONST,
  OFF_EX   = OFF_CUT + E_CONST,
  OFF_FLAG = OFF_EX + E_CONST,   // int flag stored in a float slot
  OFF_WT   = (OFF_FLAG + 7) & ~3,  // bf16 Wt [2 layers][576 cols][64 k] (36864 f32 slots)
};

// ---------------- dtype detection ----------------
__global__ void k_detect(const unsigned int* __restrict__ words, int* __restrict__ flag) {
  if (blockIdx.x != 0 || threadIdx.x != 0) return;
  int cnt = 0;
  for (int i = 0; i < 512; ++i) {
    unsigned b = (words[i] >> 8) & 0x7Fu;
    cnt += (b >= 0x3Au && b <= 0x43u) ? 1 : 0;
  }
  *flag = (cnt > 256) ? 1 : 0;
}

// ---------------- convert all float inputs to f32 in ws ----------------
struct CvtArgs {
  const void* src[16];
  int n[16];
  int off[16];
};

template <bool BF>
__global__ void k_cvt(CvtArgs a, float* __restrict__ ws, const int* __restrict__ flag) {
  if ((*flag != 0) != BF) return;
  int tid = blockIdx.x * blockDim.x + threadIdx.x;
  int stride = gridDim.x * blockDim.x;
  for (int arr = 0; arr < 16; ++arr) {
    float* dst = ws + a.off[arr];
    int n = a.n[arr];
    if (BF) {
      const __hip_bfloat16* s = (const __hip_bfloat16*)a.src[arr];
      for (int i = tid; i < n; i += stride) dst[i] = __bfloat162float(s[i]);
    } else {
      const float* s = (const float*)a.src[arr];
      for (int i = tid; i < n; i += stride) dst[i] = s[i];
    }
  }
}

// ---------------- helpers ----------------
DEV unsigned short f2bf(float f) {   // RNE f32 -> bf16 bits
  unsigned int u = __float_as_uint(f);
  u = u + 0x7FFFu + ((u >> 16) & 1u);
  return (unsigned short)(u >> 16);
}

DEV void atomicMaxF(float* addr, float val) {
  unsigned int* ai = (unsigned int*)addr;
  unsigned int old = *ai;
  while (__uint_as_float(old) < val) {
    unsigned int assumed = old;
    old = atomicCAS(ai, assumed, __float_as_uint(val));
    if (old == assumed) break;
  }
}

// e3nn o3.Linear on 16x0e+8x1o input -> MO0 x0e + MO1 x1o
template <int MO0, int MO1>
DEV void lin_apply(const float* __restrict__ in40, const float* __restrict__ W0,
                   const float* __restrict__ W1, float* __restrict__ out) {
#pragma unroll
  for (int j = 0; j < MO0; ++j) {
    float a = 0.f;
#pragma unroll
    for (int i = 0; i < 16; ++i) a += in40[i] * W0[i * MO0 + j];
    out[j] = a * INV16SQ;
  }
#pragma unroll
  for (int w = 0; w < MO1; ++w) {
    float a0 = 0.f, a1 = 0.f, a2 = 0.f;
#pragma unroll
    for (int u = 0; u < 8; ++u) {
      float wt = W1[u * MO1 + w];
      a0 += in40[16 + u * 3 + 0] * wt;
      a1 += in40[16 + u * 3 + 1] * wt;
      a2 += in40[16 + u * 3 + 2] * wt;
    }
    out[MO0 + w * 3 + 0] = a0 * INV8SQ;
    out[MO0 + w * 3 + 1] = a1 * INV8SQ;
    out[MO0 + w * 3 + 2] = a2 * INV8SQ;
  }
}

DEV void edge_emb(float d, float emb[16]) {
#pragma unroll
  for (int i = 0; i < 16; ++i) {
    float c = (2.0f * (i + 1)) / 17.0f;
    float df = (d - c) * (17.0f * 0.5f);
    emb[i] = __expf(-df * df) * (4.0f / 1.12f);
  }
}

// hidden slice: this WAVE computes h for k in [wv*16, wv*16+16); wv is wave-uniform
DEV void radial_hidden16(const float* __restrict__ W1, const float emb[16],
                         int wv, float h[16]) {
#pragma unroll 1
  for (int i = 0; i < 16; ++i) {
    float a = 0.f;
#pragma unroll
    for (int j = 0; j < 16; ++j) a += emb[j] * W1[j * 64 + wv * 16 + i];
    a *= INV16SQ;
    float sig = 1.0f / (1.0f + __expf(-a));
    h[i] = a * sig * HID_SC;
  }
}

// shared per-edge prologue: geometry + features of source node
struct EdgeCtx {
  float y1[3], d;
  float fs[16];
  float fv[8][3];
  float vy[8];
};

DEV void edge_prologue(const float* __restrict__ pos, const float* __restrict__ x,
                       int s, int t, EdgeCtx& c) {
  float vx = pos[s * 3 + 0] - pos[t * 3 + 0];
  float vyy = pos[s * 3 + 1] - pos[t * 3 + 1];
  float vz = pos[s * 3 + 2] - pos[t * 3 + 2];
  c.d = sqrtf(vx * vx + vyy * vyy + vz * vz + 1e-24f);
  float inv = SQ3F / c.d;
  c.y1[0] = vx * inv; c.y1[1] = vyy * inv; c.y1[2] = vz * inv;

  const float* xs = x + s * 40;
#pragma unroll
  for (int i = 0; i < 16; ++i) c.fs[i] = xs[i];
#pragma unroll
  for (int u = 0; u < 8; ++u) {
    c.fv[u][0] = xs[16 + u * 3 + 0];
    c.fv[u][1] = xs[16 + u * 3 + 1];
    c.fv[u][2] = xs[16 + u * 3 + 2];
  }
#pragma unroll
  for (int u = 0; u < 8; ++u)
    c.vy[u] = (c.fv[u][0] * c.y1[0] + c.fv[u][1] * c.y1[1] + c.fv[u][2] * c.y1[2]) * INV_SQ3F;
}

// ---------------- weight transpose to bf16: Wt[l][col][k] ----------------
__global__ void k_wt(const float* __restrict__ fcv2, unsigned short* __restrict__ wt) {
  int tid = blockIdx.x * blockDim.x + threadIdx.x;
  if (tid >= 2 * 576 * 64) return;
  int l = tid / 36864;
  int r = tid - l * 36864;
  int c = r >> 6;
  int k = r & 63;
  wt[tid] = f2bf(fcv2[l * 36864 + k * 576 + c]);
}

// ---------------- node kernels ----------------
__global__ void k_lin_in(const float* __restrict__ f, const float* __restrict__ W0,
                         const float* __restrict__ W1, float* __restrict__ x, int N) {
  int n = blockIdx.x * blockDim.x + threadIdx.x;
  if (n >= N) return;
  lin_apply<16, 8>(f + n * 40, W0, W1, x + n * 40);
}

__global__ void k_q(const float* __restrict__ x, const float* __restrict__ W0,
                    const float* __restrict__ W1, float* __restrict__ q, int N) {
  int n = blockIdx.x * blockDim.x + threadIdx.x;
  if (n >= N) return;
  lin_apply<8, 4>(x + n * 40, W0, W1, q + n * 20);
}

__global__ void k_init(float* __restrict__ mx, float* __restrict__ z,
                       float* __restrict__ agg, int N) {
  int i = blockIdx.x * blockDim.x + threadIdx.x;
  if (i < N * 40) agg[i] = 0.f;
  if (i < N) { mx[i] = -INFINITY; z[i] = 0.f; }
}

__global__ void k_update(float* __restrict__ x, const float* __restrict__ agg, int n) {
  int i = blockIdx.x * blockDim.x + threadIdx.x;
  if (i < n) x[i] += agg[i];
}

// ---------------- edge kernel 1: K path + logits (unchanged) ----------------
__global__ void __launch_bounds__(256)
k_edge_k(const float* __restrict__ pos, const float* __restrict__ x,
         const float* __restrict__ q,
         const float* __restrict__ fck1, const float* __restrict__ fck2,
         const float* __restrict__ dot0, const float* __restrict__ dot1,
         const int* __restrict__ srcv, const int* __restrict__ dstv,
         float* __restrict__ logit, float* __restrict__ cutb,
         float* __restrict__ mx, int E) {
  __shared__ float acc[64 * 25];   // [edge][0:8 ks | 8:12 a2 | 12:24 a3], stride 25
  __shared__ float y1s[64 * 3];

  const int tid = threadIdx.x;
  const int wv = __builtin_amdgcn_readfirstlane(tid >> 6);
  const int lane = tid & 63;
  const int e0 = blockIdx.x * 64;
  const int e = e0 + lane;
  const bool valid = e < E;

  for (int i = tid; i < 64 * 25; i += 256) acc[i] = 0.f;
  __syncthreads();

  int s = valid ? srcv[e] : 0, t = valid ? dstv[e] : 0;
  EdgeCtx c;
  edge_prologue(pos, x, s, t, c);
  float emb[16];
  edge_emb(c.d, emb);

  if (wv == 0 && valid) {
    float uu = 10.0f * (1.0f - 0.5f * c.d);
    cutb[e] = (uu > 0.f) ? __expf(-1.0f / fmaxf(uu, 1e-9f)) : 0.f;
    y1s[lane * 3 + 0] = c.y1[0];
    y1s[lane * 3 + 1] = c.y1[1];
    y1s[lane * 3 + 2] = c.y1[2];
  }

  float h[16];
  radial_hidden16(fck1, emb, wv, h);

  float ks[8] = {0}, a2[4] = {0}, a3[4][3] = {{0}};
#pragma unroll 1
  for (int i = 0; i < 16; ++i) {
    float hk = h[i];
    const float* r = fck2 + (wv * 16 + i) * 288;
#pragma unroll
    for (int u = 0; u < 16; ++u) {
      float fu = hk * c.fs[u];
#pragma unroll
      for (int w = 0; w < 8; ++w) ks[w] += fu * r[u * 8 + w];
    }
#pragma unroll
    for (int u = 0; u < 16; ++u) {
      float fu = hk * c.fs[u];
#pragma unroll
      for (int w = 0; w < 4; ++w) a2[w] += fu * r[128 + u * 4 + w];
    }
#pragma unroll
    for (int u = 0; u < 8; ++u) {
      float c0 = hk * c.fv[u][0], c1 = hk * c.fv[u][1], c2 = hk * c.fv[u][2];
#pragma unroll
      for (int w = 0; w < 4; ++w) {
        float wt = r[192 + u * 4 + w];
        a3[w][0] += c0 * wt; a3[w][1] += c1 * wt; a3[w][2] += c2 * wt;
      }
    }
#pragma unroll
    for (int u = 0; u < 8; ++u) {
      float vu = hk * c.vy[u];
#pragma unroll
      for (int w = 0; w < 8; ++w) ks[w] += vu * r[224 + u * 8 + w];
    }
  }

  if (valid) {
    float* a = acc + lane * 25;
#pragma unroll
    for (int w = 0; w < 8; ++w) atomicAdd(&a[w], ks[w]);
#pragma unroll
    for (int w = 0; w < 4; ++w) atomicAdd(&a[8 + w], a2[w]);
#pragma unroll
    for (int w = 0; w < 4; ++w)
#pragma unroll
      for (int i = 0; i < 3; ++i) atomicAdd(&a[12 + w * 3 + i], a3[w][i]);
  }
  __syncthreads();

  if (tid < 64) {
    int ee = e0 + tid;
    if (ee < E) {
      int tt = dstv[ee];
      const float* a = acc + tid * 25;
      float yy0 = y1s[tid * 3 + 0], yy1 = y1s[tid * 3 + 1], yy2 = y1s[tid * 3 + 2];
      const float* qd = q + tt * 20;
      float lg = 0.f;
#pragma unroll
      for (int u = 0; u < 8; ++u) {
        float qu = qd[u] * FAN_TP;
#pragma unroll
        for (int v = 0; v < 8; ++v) lg += qu * a[v] * dot0[u * 8 + v];
      }
#pragma unroll
      for (int v = 0; v < 4; ++v) {
        float k0 = a[8 + v] * yy0 * FAN_TP + a[12 + v * 3 + 0] * FAN_TP_V;
        float k1 = a[8 + v] * yy1 * FAN_TP + a[12 + v * 3 + 1] * FAN_TP_V;
        float k2 = a[8 + v] * yy2 * FAN_TP + a[12 + v * 3 + 2] * FAN_TP_V;
#pragma unroll
        for (int u = 0; u < 4; ++u) {
          float wt = dot1[u * 4 + v] * INV_SQ3F;
          lg += (qd[8 + u * 3 + 0] * k0 + qd[8 + u * 3 + 1] * k1 +
                 qd[8 + u * 3 + 2] * k2) * wt;
        }
      }
      lg *= FAN_DOT;
      logit[ee] = lg;
      atomicMaxF(&mx[tt], lg);
    }
  }
}

// ---------------- edge kernel 2: exp + denominator ----------------
__global__ void k_edge_ex(const int* __restrict__ dstv, const float* __restrict__ logit,
                          const float* __restrict__ cutb, const float* __restrict__ mx,
                          float* __restrict__ ex, float* __restrict__ z, int E) {
  int e = blockIdx.x * blockDim.x + threadIdx.x;
  if (e >= E) return;
  int t = dstv[e];
  float m = mx[t];
  if (m == -INFINITY) m = 0.f;
  float v = cutb[e] * __expf(logit[e] - m);
  ex[e] = v;
  atomicAdd(&z[t], v);
}

// ---------------- edge kernel 3: V path via MFMA ----------------
// block = 256 thr = 4 waves, 64 edges. GEMM: C[64 e][576 c] = h[64 e][64 k] @ W[64 k][576 c]
// done as 3 passes x 192 cols; wave wv owns N-tiles {pass*12 + wv + 4t}.
// A-frag (mfma_f32_16x16x32_bf16): lane l -> A[row=l%16][k=8*(l/16)+j]
// B-frag: lane l -> B[k=8*(l/16)+j][col=l%16]   (Wt is [col][k] so frag is contiguous)
// C/D  : lane l -> D[row=4*(l/16)+j][col=l%16]  (verified layout)
__global__ void __launch_bounds__(256)
k_edge_v(const float* __restrict__ pos, const float* __restrict__ x,
         const float* __restrict__ fcv1, const unsigned short* __restrict__ wt,
         const int* __restrict__ srcv, const int* __restrict__ dstv,
         const float* __restrict__ ex, const float* __restrict__ z,
         float* __restrict__ agg, int E) {
  __shared__ unsigned short h_lds[64 * 80];  // [edge][k], stride 80 (16B-aligned rows)
  __shared__ float feat[64 * 56];            // [edge][0:40 xs | 40:48 vy | 48:51 y1]
  __shared__ float cbuf[64 * 200];           // [edge][192 cols + pad]

  const int tid = threadIdx.x;
  const int wv = __builtin_amdgcn_readfirstlane(tid >> 6);
  const int lane = tid & 63;
  const int e0 = blockIdx.x * 64;
  const int eL = e0 + lane;
  const bool valid = eL < E;

  int s = valid ? srcv[eL] : 0, t = valid ? dstv[eL] : 0;

  // geometry -> d -> emb (every wave, own edge)
  float y1v[3], d;
  {
    float vx = pos[s * 3 + 0] - pos[t * 3 + 0];
    float vy_ = pos[s * 3 + 1] - pos[t * 3 + 1];
    float vz = pos[s * 3 + 2] - pos[t * 3 + 2];
    d = sqrtf(vx * vx + vy_ * vy_ + vz * vz + 1e-24f);
    float inv = SQ3F / d;
    y1v[0] = vx * inv; y1v[1] = vy_ * inv; y1v[2] = vz * inv;
  }
  float emb[16];
  edge_emb(d, emb);

  // h slice for this wave's k-range
  float h[16];
  radial_hidden16(fcv1, emb, wv, h);

  // pack to bf16, write 32B to h_lds[lane][16*wv ..]
  {
    unsigned int hw[8];
#pragma unroll
    for (int i = 0; i < 8; ++i)
      hw[i] = (unsigned int)f2bf(h[2 * i]) | ((unsigned int)f2bf(h[2 * i + 1]) << 16);
    uint4 w0 = {hw[0], hw[1], hw[2], hw[3]};
    uint4 w1 = {hw[4], hw[5], hw[6], hw[7]};
    *(uint4*)&h_lds[lane * 80 + 16 * wv] = w0;
    *(uint4*)&h_lds[lane * 80 + 16 * wv + 8] = w1;
  }

  // wave 0: stage per-edge features (xs raw 40, vy, y1)
  if (wv == 0) {
    const float* xs = x + s * 40;
    float* fl = feat + lane * 56;
#pragma unroll
    for (int k4 = 0; k4 < 10; ++k4)
      *(float4*)&fl[k4 * 4] = *(const float4*)&xs[k4 * 4];
#pragma unroll
    for (int u = 0; u < 8; ++u) {
      float vyu = (fl[16 + u * 3 + 0] * y1v[0] + fl[16 + u * 3 + 1] * y1v[1] +
                   fl[16 + u * 3 + 2] * y1v[2]) * INV_SQ3F;
      fl[40 + u] = vyu;
    }
    fl[48] = y1v[0]; fl[49] = y1v[1]; fl[50] = y1v[2];
  }

  __syncthreads();

  // A fragments: 4 M-tiles x 2 K-steps, reused across all passes
  bf16x8 afrag[4][2];
#pragma unroll
  for (int mt = 0; mt < 4; ++mt)
#pragma unroll
    for (int ks = 0; ks < 2; ++ks) {
      uint4 a = *(const uint4*)&h_lds[(16 * mt + (lane & 15)) * 80 + 32 * ks + 8 * (lane >> 4)];
      afrag[mt][ks] = __builtin_bit_cast(bf16x8, a);
    }

  // epilogue accumulators (persist across passes); thread = (edge ep, part p)
  const int ep = tid >> 2;
  const int p = tid & 3;
  float vs_loc[4] = {0.f, 0.f, 0.f, 0.f};
  float b2_loc[4] = {0.f, 0.f, 0.f, 0.f};
  float b3_loc[4][3] = {{0.f}};

#pragma unroll 1
  for (int pass = 0; pass < 3; ++pass) {
    // ---- GEMM phase ----
    f32x4 acc[4][3];
#pragma unroll
    for (int mt = 0; mt < 4; ++mt)
#pragma unroll
      for (int tt = 0; tt < 3; ++tt) acc[mt][tt] = {0.f, 0.f, 0.f, 0.f};

#pragma unroll
    for (int tt = 0; tt < 3; ++tt) {
      int ntile = pass * 12 + wv + 4 * tt;
      const unsigned short* bsrc = wt + (ntile * 16 + (lane & 15)) * 64 + 8 * (lane >> 4);
#pragma unroll
      for (int ks = 0; ks < 2; ++ks) {
        uint4 braw = *(const uint4*)(bsrc + 32 * ks);
        bf16x8 bfrag = __builtin_bit_cast(bf16x8, braw);
#pragma unroll
        for (int mt = 0; mt < 4; ++mt)
          acc[mt][tt] = __builtin_amdgcn_mfma_f32_16x16x32_bf16(
              afrag[mt][ks], bfrag, acc[mt][tt], 0, 0, 0);
      }
    }

    // C store: rows 16*mt + 4*(lane>>4)+j, local col (wv+4*tt)*16 + (lane&15)
#pragma unroll
    for (int tt = 0; tt < 3; ++tt) {
      int colL = (wv + 4 * tt) * 16 + (lane & 15);
#pragma unroll
      for (int mt = 0; mt < 4; ++mt) {
        int row = 16 * mt + 4 * (lane >> 4);
#pragma unroll
        for (int j = 0; j < 4; ++j)
          cbuf[(row + j) * 200 + colL] = acc[mt][tt][j];
      }
    }
    __syncthreads();

    // ---- epilogue phase: contract this pass's 192 cols ----
    {
      const float* fl = feat + ep * 56;
#pragma unroll
      for (int m = 0; m < 12; ++m) {
        int c0 = pass * 192 + p * 4 + 16 * m;
        f32x4 f4 = *(const f32x4*)&cbuf[ep * 200 + p * 4 + 16 * m];
        if (c0 < 256) {                       // W1: vs += fs[u]*M
          float f = fl[c0 >> 4];
#pragma unroll
          for (int j = 0; j < 4; ++j) vs_loc[j] += f * f4[j];
        } else if (c0 < 384) {                // W2: b2 += fs[u]*M
          float f = fl[(c0 - 256) >> 3];
#pragma unroll
          for (int j = 0; j < 4; ++j) b2_loc[j] += f * f4[j];
        } else if (c0 < 448) {                // W3: b3 += fv[u][i]*M
          int u = (c0 - 384) >> 3;
#pragma unroll
          for (int j = 0; j < 4; ++j)
#pragma unroll
            for (int i = 0; i < 3; ++i) b3_loc[j][i] += fl[16 + u * 3 + i] * f4[j];
        } else {                              // W4: vs += vy[u]*M
          float f = fl[40 + ((c0 - 448) >> 4)];
#pragma unroll
          for (int j = 0; j < 4; ++j) vs_loc[j] += f * f4[j];
        }
      }
    }
    __syncthreads();
  }

  // ---- final: weight by attention, reduce partners, scatter ----
  int ee = e0 + ep;
  if (ee < E) {
    int tt = dstv[ee];
    float zz = z[tt];
    zz = (zz == 0.f) ? 1.f : zz;
    float alpha = ex[ee] / zz;
    float wgt = sqrtf(alpha + 1e-12f);
    const float* fl = feat + ep * 56;
    float yy[3] = {fl[48], fl[49], fl[50]};

    float b2r[4], b3r[4][3];
#pragma unroll
    for (int j = 0; j < 4; ++j) b2r[j] = b2_loc[j] + __shfl_xor(b2_loc[j], 2);
#pragma unroll
    for (int j = 0; j < 4; ++j)
#pragma unroll
      for (int i = 0; i < 3; ++i) b3r[j][i] = b3_loc[j][i] + __shfl_xor(b3_loc[j][i], 2);

    float* at = agg + tt * 40;
#pragma unroll
    for (int j = 0; j < 4; ++j)
      atomicAdd(&at[4 * p + j], wgt * vs_loc[j] * FAN_TP);

    int w0 = 4 * (p & 1);
    if (p < 2) {
#pragma unroll
      for (int j = 0; j < 4; ++j)
#pragma unroll
        for (int i = 0; i < 2; ++i) {
          float v = b2r[j] * yy[i] * FAN_TP + b3r[j][i] * FAN_TP_V;
          atomicAdd(&at[16 + (w0 + j) * 3 + i], wgt * v);
        }
    } else {
#pragma unroll
      for (int j = 0; j < 4; ++j) {
        float v = b2r[j] * yy[2] * FAN_TP + b3r[j][2] * FAN_TP_V;
        atomicAdd(&at[16 + (w0 + j) * 3 + 2], wgt * v);
      }
    }
  }
}

// ---------------- output kernel ----------------
template <bool BF>
__global__ void k_out(const float* __restrict__ x, const float* __restrict__ rb0,
                      const float* __restrict__ rb1, const float* __restrict__ re0,
                      const float* __restrict__ re1, void* __restrict__ out, int N,
                      const int* __restrict__ flag) {
  if ((*flag != 0) != BF) return;
  int n = blockIdx.x * blockDim.x + threadIdx.x;
  if (n >= N) return;
  float b[20], eta[20];
  lin_apply<8, 4>(x + n * 40, rb0, rb1, b);
  lin_apply<8, 4>(x + n * 40, re0, re1, eta);
  if (BF) {
    __hip_bfloat16* o = (__hip_bfloat16*)out;
#pragma unroll
    for (int j = 0; j < 20; ++j) o[n * 20 + j] = __float2bfloat16(b[j]);
#pragma unroll
    for (int j = 0; j < 20; ++j) o[N * 20 + n * 20 + j] = __float2bfloat16(eta[j]);
  } else {
    float* o = (float*)out;
#pragma unroll
    for (int j = 0; j < 20; ++j) o[n * 20 + j] = b[j];
#pragma unroll
    for (int j = 0; j < 20; ++j) o[N * 20 + n * 20 + j] = eta[j];
  }
}

// ---------------- host ----------------
extern "C" void kernel_launch(void* const* d_in, const int* in_sizes, int n_in,
                              void* d_out, int out_size, void* d_ws, size_t ws_size,
                              hipStream_t stream) {
  float* ws = (float*)d_ws;
  const int N = in_sizes[0] / 40;
  const int E = in_sizes[16];
  const int* src = (const int*)d_in[16];
  const int* dst = (const int*)d_in[17];
  int* flag = (int*)(ws + OFF_FLAG);
  unsigned short* wt = (unsigned short*)(ws + OFF_WT);

  k_detect<<<1, 64, 0, stream>>>((const unsigned int*)d_in[0], flag);

  CvtArgs ca;
  const int order[16] = {2, 3, 4, 5, 6, 7, 8, 9, 10, 11, 12, 13, 14, 15, 0, 1};
  const int offs[16] = {OFF_LIN0, OFF_LIN1, OFF_HQ0, OFF_HQ1, OFF_FCK1, OFF_FCK2,
                        OFF_FCV1, OFF_FCV2, OFF_DOT0, OFF_DOT1, OFF_RB0, OFF_RB1,
                        OFF_RE0, OFF_RE1, OFF_F, OFF_POS};
  for (int i = 0; i < 16; ++i) {
    ca.src[i] = d_in[order[i]];
    ca.n[i] = in_sizes[order[i]];
    ca.off[i] = offs[i];
  }
  k_cvt<false><<<512, 256, 0, stream>>>(ca, ws, flag);
  k_cvt<true><<<512, 256, 0, stream>>>(ca, ws, flag);
  k_wt<<<(2 * 576 * 64 + 255) / 256, 256, 0, stream>>>(ws + OFF_FCV2, wt);

  float* x = ws + OFF_X;
  float* q = ws + OFF_Q;
  float* mx = ws + OFF_MX;
  float* z = ws + OFF_Z;
  float* agg = ws + OFF_AGG;
  float* logit = ws + OFF_LOGIT;
  float* cutb = ws + OFF_CUT;
  float* exb = ws + OFF_EX;
  const float* pos = ws + OFF_POS;

  const int nodeBlocks = (N + 255) / 256;
  const int vecBlocks = (N * 40 + 255) / 256;
  const int edgeBlocks = (E + 255) / 256;
  const int eb64 = (E + 63) / 64;   // block = 64 edges

  k_lin_in<<<nodeBlocks, 256, 0, stream>>>(ws + OFF_F, ws + OFF_LIN0, ws + OFF_LIN1, x, N);

  for (int l = 0; l < 2; ++l) {
    k_init<<<vecBlocks, 256, 0, stream>>>(mx, z, agg, N);
    k_q<<<nodeBlocks, 256, 0, stream>>>(x, ws + OFF_HQ0 + l * 128, ws + OFF_HQ1 + l * 32, q, N);
    k_edge_k<<<eb64, 256, 0, stream>>>(
        pos, x, q, ws + OFF_FCK1 + l * 1024, ws + OFF_FCK2 + l * 18432,
        ws + OFF_DOT0 + l * 64, ws + OFF_DOT1 + l * 16, src, dst, logit, cutb, mx, E);
    k_edge_ex<<<edgeBlocks, 256, 0, stream>>>(dst, logit, cutb, mx, exb, z, E);
    k_edge_v<<<eb64, 256, 0, stream>>>(
        pos, x, ws + OFF_FCV1 + l * 1024, wt + l * 36864, src, dst, exb, z, agg, E);
    k_update<<<vecBlocks, 256, 0, stream>>>(x, agg, N * 40);
  }

  k_out<false><<<nodeBlocks, 256, 0, stream>>>(x, ws + OFF_RB0, ws + OFF_RB1,
                                               ws + OFF_RE0, ws + OFF_RE1, d_out, N, flag);
  k_out<true><<<nodeBlocks, 256, 0, stream>>>(x, ws + OFF_RB0, ws + OFF_RB1,
                                              ws + OFF_RE0, ws + OFF_RE1, d_out, N, flag);
}

// Round 5
// 383.743 us; speedup vs baseline: 17.7062x; 1.9529x over previous
//
#include <hip/hip_runtime.h>
#include <hip/hip_bf16.h>
#include <math.h>

#define DEV __device__ __forceinline__

typedef __attribute__((ext_vector_type(4))) float f32x4;
typedef __attribute__((ext_vector_type(8))) __bf16 bf16x8;

// ---------------- problem constants ----------------
constexpr int N_CONST = 8192;
constexpr int E_CONST = 131072;

constexpr float SQ3F     = 1.7320508075688772f;
constexpr float INV_SQ3F = 0.57735026918962576f;
constexpr float FAN_TP   = 0.20412414523193150f;   // 24^-0.5
constexpr float FAN_TP_V = 0.35355339059327373f;   // sqrt(3)*24^-0.5
constexpr float FAN_DOT  = 0.11180339887498949f;   // 80^-0.5
constexpr float INV16SQ  = 0.25f;                  // 16^-0.5
constexpr float INV8SQ   = 0.35355339059327373f;   // 8^-0.5
constexpr float HID_SC   = 0.125f;                 // 64^-0.5

// ---------------- workspace layout (float offsets) ----------------
enum : int {
  OFF_LIN0 = 0,
  OFF_LIN1 = OFF_LIN0 + 256,
  OFF_HQ0  = OFF_LIN1 + 64,
  OFF_HQ1  = OFF_HQ0 + 256,
  OFF_FCK1 = OFF_HQ1 + 64,
  OFF_FCK2 = OFF_FCK1 + 2048,
  OFF_FCV1 = OFF_FCK2 + 36864,
  OFF_FCV2 = OFF_FCV1 + 2048,
  OFF_DOT0 = OFF_FCV2 + 73728,
  OFF_DOT1 = OFF_DOT0 + 128,
  OFF_RB0  = OFF_DOT1 + 32,
  OFF_RB1  = OFF_RB0 + 128,
  OFF_RE0  = OFF_RB1 + 32,
  OFF_RE1  = OFF_RE0 + 128,
  OFF_F    = OFF_RE1 + 32,
  OFF_POS  = OFF_F + N_CONST * 40,
  OFF_X    = OFF_POS + N_CONST * 3,
  OFF_Q    = OFF_X + N_CONST * 40,
  OFF_MX   = OFF_Q + N_CONST * 20,
  OFF_Z    = OFF_MX + N_CONST,
  OFF_AGG  = OFF_Z + N_CONST,
  OFF_LOGIT= OFF_AGG + N_CONST * 40,
  OFF_CUT  = OFF_LOGIT + E_CONST,
  OFF_EX   = OFF_CUT + E_CONST,
  OFF_FLAG = OFF_EX + E_CONST,     // int flag stored in a float slot
  OFF_WT   = (OFF_FLAG + 7) & ~3,  // bf16 WtV [2][576 cols][64 k] (36864 f32 slots)
  OFF_WTK  = OFF_WT + 36864,       // bf16 WtK [2][288 cols][64 k] (18432 f32 slots)
};

// ---------------- dtype detection ----------------
__global__ void k_detect(const unsigned int* __restrict__ words, int* __restrict__ flag) {
  if (blockIdx.x != 0 || threadIdx.x != 0) return;
  int cnt = 0;
  for (int i = 0; i < 512; ++i) {
    unsigned b = (words[i] >> 8) & 0x7Fu;
    cnt += (b >= 0x3Au && b <= 0x43u) ? 1 : 0;
  }
  *flag = (cnt > 256) ? 1 : 0;
}

// ---------------- convert all float inputs to f32 in ws ----------------
struct CvtArgs {
  const void* src[16];
  int n[16];
  int off[16];
};

template <bool BF>
__global__ void k_cvt(CvtArgs a, float* __restrict__ ws, const int* __restrict__ flag) {
  if ((*flag != 0) != BF) return;
  int tid = blockIdx.x * blockDim.x + threadIdx.x;
  int stride = gridDim.x * blockDim.x;
  for (int arr = 0; arr < 16; ++arr) {
    float* dst = ws + a.off[arr];
    int n = a.n[arr];
    if (BF) {
      const __hip_bfloat16* s = (const __hip_bfloat16*)a.src[arr];
      for (int i = tid; i < n; i += stride) dst[i] = __bfloat162float(s[i]);
    } else {
      const float* s = (const float*)a.src[arr];
      for (int i = tid; i < n; i += stride) dst[i] = s[i];
    }
  }
}

// ---------------- helpers ----------------
DEV unsigned short f2bf(float f) {   // RNE f32 -> bf16 bits
  unsigned int u = __float_as_uint(f);
  u = u + 0x7FFFu + ((u >> 16) & 1u);
  return (unsigned short)(u >> 16);
}

DEV void atomicMaxF(float* addr, float val) {
  unsigned int* ai = (unsigned int*)addr;
  unsigned int old = *ai;
  while (__uint_as_float(old) < val) {
    unsigned int assumed = old;
    old = atomicCAS(ai, assumed, __float_as_uint(val));
    if (old == assumed) break;
  }
}

// e3nn o3.Linear on 16x0e+8x1o input -> MO0 x0e + MO1 x1o
template <int MO0, int MO1>
DEV void lin_apply(const float* __restrict__ in40, const float* __restrict__ W0,
                   const float* __restrict__ W1, float* __restrict__ out) {
#pragma unroll
  for (int j = 0; j < MO0; ++j) {
    float a = 0.f;
#pragma unroll
    for (int i = 0; i < 16; ++i) a += in40[i] * W0[i * MO0 + j];
    out[j] = a * INV16SQ;
  }
#pragma unroll
  for (int w = 0; w < MO1; ++w) {
    float a0 = 0.f, a1 = 0.f, a2 = 0.f;
#pragma unroll
    for (int u = 0; u < 8; ++u) {
      float wt = W1[u * MO1 + w];
      a0 += in40[16 + u * 3 + 0] * wt;
      a1 += in40[16 + u * 3 + 1] * wt;
      a2 += in40[16 + u * 3 + 2] * wt;
    }
    out[MO0 + w * 3 + 0] = a0 * INV8SQ;
    out[MO0 + w * 3 + 1] = a1 * INV8SQ;
    out[MO0 + w * 3 + 2] = a2 * INV8SQ;
  }
}

DEV void edge_emb(float d, float emb[16]) {
#pragma unroll
  for (int i = 0; i < 16; ++i) {
    float c = (2.0f * (i + 1)) / 17.0f;
    float df = (d - c) * (17.0f * 0.5f);
    emb[i] = __expf(-df * df) * (4.0f / 1.12f);
  }
}

// hidden slice: this WAVE computes h for k in [wv*16, wv*16+16); wv is wave-uniform
DEV void radial_hidden16(const float* __restrict__ W1, const float emb[16],
                         int wv, float h[16]) {
#pragma unroll 1
  for (int i = 0; i < 16; ++i) {
    float a = 0.f;
#pragma unroll
    for (int j = 0; j < 16; ++j) a += emb[j] * W1[j * 64 + wv * 16 + i];
    a *= INV16SQ;
    float sig = 1.0f / (1.0f + __expf(-a));
    h[i] = a * sig * HID_SC;
  }
}

// 2 chained MFMAs over the k=64 dimension for one 16-col N-tile
DEV f32x4 gemm2(const unsigned short* __restrict__ wtb, int T, int c, int g,
                bf16x8 a0, bf16x8 a1) {
  const unsigned short* bsrc = wtb + (T * 16 + c) * 64 + 8 * g;
  bf16x8 b0 = __builtin_bit_cast(bf16x8, *(const uint4*)(bsrc));
  bf16x8 b1 = __builtin_bit_cast(bf16x8, *(const uint4*)(bsrc + 32));
  f32x4 acc = __builtin_amdgcn_mfma_f32_16x16x32_bf16(a0, b0, (f32x4){0.f, 0.f, 0.f, 0.f}, 0, 0, 0);
  return __builtin_amdgcn_mfma_f32_16x16x32_bf16(a1, b1, acc, 0, 0, 0);
}

// ---------------- weight transposes to bf16 ----------------
__global__ void k_wt(const float* __restrict__ fcv2, unsigned short* __restrict__ wt) {
  int tid = blockIdx.x * blockDim.x + threadIdx.x;
  if (tid >= 2 * 576 * 64) return;
  int l = tid / 36864;
  int r = tid - l * 36864;
  int c = r >> 6;
  int k = r & 63;
  wt[tid] = f2bf(fcv2[l * 36864 + k * 576 + c]);
}

__global__ void k_wtk(const float* __restrict__ fck2, unsigned short* __restrict__ wtk) {
  int tid = blockIdx.x * blockDim.x + threadIdx.x;
  if (tid >= 2 * 288 * 64) return;
  int l = tid / 18432;
  int r = tid - l * 18432;
  int c = r >> 6;
  int k = r & 63;
  wtk[tid] = f2bf(fck2[l * 18432 + k * 288 + c]);
}

// ---------------- node kernels ----------------
__global__ void k_lin_in(const float* __restrict__ f, const float* __restrict__ W0,
                         const float* __restrict__ W1, float* __restrict__ x, int N) {
  int n = blockIdx.x * blockDim.x + threadIdx.x;
  if (n >= N) return;
  lin_apply<16, 8>(f + n * 40, W0, W1, x + n * 40);
}

__global__ void k_q(const float* __restrict__ x, const float* __restrict__ W0,
                    const float* __restrict__ W1, float* __restrict__ q, int N) {
  int n = blockIdx.x * blockDim.x + threadIdx.x;
  if (n >= N) return;
  lin_apply<8, 4>(x + n * 40, W0, W1, q + n * 20);
}

__global__ void k_init(float* __restrict__ mx, float* __restrict__ z,
                       float* __restrict__ agg, int N) {
  int i = blockIdx.x * blockDim.x + threadIdx.x;
  if (i < N * 40) agg[i] = 0.f;
  if (i < N) { mx[i] = -INFINITY; z[i] = 0.f; }
}

__global__ void k_update(float* __restrict__ x, const float* __restrict__ agg, int n) {
  int i = blockIdx.x * blockDim.x + threadIdx.x;
  if (i < n) x[i] += agg[i];
}

// ---------------- edge kernel 1: K path + logits (MFMA, fused) ----------------
// block = 4 waves = 64 edges. Wave wv owns M-tile wv (16 edges) and all 18 N-tiles
// of C[64e][288c] = h[64e][64k] @ Wk[64k][288c]. The u-contraction with fs/fv/vy is
// fused per-tile in-register; logit assembled via group shfl butterfly.
__global__ void __launch_bounds__(256)
k_edge_k(const float* __restrict__ pos, const float* __restrict__ x,
         const float* __restrict__ q,
         const float* __restrict__ fck1, const unsigned short* __restrict__ wtk,
         const float* __restrict__ dot0, const float* __restrict__ dot1,
         const int* __restrict__ srcv, const int* __restrict__ dstv,
         float* __restrict__ logit, float* __restrict__ cutb,
         float* __restrict__ mx, int E) {
  __shared__ alignas(16) unsigned short h_lds[64 * 72];  // [edge][k] stride 72
  __shared__ float fS[48][64];   // fields: fs 0..15 | fv 16..39 | vy 40..47
  __shared__ float y1A[64][4];
  __shared__ float qdA[64][8];   // FAN_DOT*FAN_TP * qs@dot0
  __shared__ float qvA[64][12];  // FAN_DOT*INV_SQ3F * qv@dot1
  __shared__ int dstA[64];

  const int tid = threadIdx.x;
  const int wv = __builtin_amdgcn_readfirstlane(tid >> 6);
  const int lane = tid & 63;
  const int e0 = blockIdx.x * 64;
  const int eL = e0 + lane;
  const bool valid = eL < E;

  int s = valid ? srcv[eL] : 0, t = valid ? dstv[eL] : 0;

  float y1v[3], d;
  {
    float vx = pos[s * 3 + 0] - pos[t * 3 + 0];
    float vy_ = pos[s * 3 + 1] - pos[t * 3 + 1];
    float vz = pos[s * 3 + 2] - pos[t * 3 + 2];
    d = sqrtf(vx * vx + vy_ * vy_ + vz * vz + 1e-24f);
    float inv = SQ3F / d;
    y1v[0] = vx * inv; y1v[1] = vy_ * inv; y1v[2] = vz * inv;
  }
  float emb[16];
  edge_emb(d, emb);
  float h[16];
  radial_hidden16(fck1, emb, wv, h);
  {
    unsigned int hw[8];
#pragma unroll
    for (int i = 0; i < 8; ++i)
      hw[i] = (unsigned int)f2bf(h[2 * i]) | ((unsigned int)f2bf(h[2 * i + 1]) << 16);
    uint4 w0 = {hw[0], hw[1], hw[2], hw[3]};
    uint4 w1 = {hw[4], hw[5], hw[6], hw[7]};
    *(uint4*)&h_lds[lane * 72 + 16 * wv] = w0;
    *(uint4*)&h_lds[lane * 72 + 16 * wv + 8] = w1;
  }

  if (wv == 0) {
    const float* xs = x + s * 40;
    float fvl[24];
#pragma unroll
    for (int i = 0; i < 16; ++i) fS[i][lane] = xs[i];
#pragma unroll
    for (int i = 0; i < 24; ++i) { fvl[i] = xs[16 + i]; fS[16 + i][lane] = fvl[i]; }
#pragma unroll
    for (int u = 0; u < 8; ++u)
      fS[40 + u][lane] = (fvl[u * 3] * y1v[0] + fvl[u * 3 + 1] * y1v[1] +
                          fvl[u * 3 + 2] * y1v[2]) * INV_SQ3F;
    y1A[lane][0] = y1v[0]; y1A[lane][1] = y1v[1]; y1A[lane][2] = y1v[2];
    dstA[lane] = t;
    if (valid) {
      float uu = 10.0f * (1.0f - 0.5f * d);
      cutb[eL] = (uu > 0.f) ? __expf(-1.0f / fmaxf(uu, 1e-9f)) : 0.f;
    }
    const float* qd_ = q + t * 20;
    float qs_[8], qv_[12];
#pragma unroll
    for (int u = 0; u < 8; ++u) qs_[u] = qd_[u];
#pragma unroll
    for (int i = 0; i < 12; ++i) qv_[i] = qd_[8 + i];
#pragma unroll
    for (int v = 0; v < 8; ++v) {
      float a = 0.f;
#pragma unroll
      for (int u = 0; u < 8; ++u) a += qs_[u] * dot0[u * 8 + v];
      qdA[lane][v] = a * (FAN_DOT * FAN_TP);
    }
#pragma unroll
    for (int v = 0; v < 4; ++v)
#pragma unroll
      for (int i = 0; i < 3; ++i) {
        float a = 0.f;
#pragma unroll
        for (int u = 0; u < 4; ++u) a += qv_[u * 3 + i] * dot1[u * 4 + v];
        qvA[lane][v * 3 + i] = a * (FAN_DOT * INV_SQ3F);
      }
  }
  __syncthreads();

  const int c = lane & 15, g = lane >> 4;
  const int erow = 16 * wv + 4 * g;   // block-local edge row for j=0

  bf16x8 a0 = __builtin_bit_cast(bf16x8, *(const uint4*)&h_lds[(16 * wv + c) * 72 + 8 * g]);
  bf16x8 a1 = __builtin_bit_cast(bf16x8, *(const uint4*)&h_lds[(16 * wv + c) * 72 + 32 + 8 * g]);

  float ksp[4] = {0.f, 0.f, 0.f, 0.f};
  float a2p[4] = {0.f, 0.f, 0.f, 0.f};
  float a3p[4][3] = {{0.f}};

  // W1k: tiles 0..7, col = 8u+w (u<16, w<8): u = 2T + (c>>3)
#pragma unroll
  for (int T = 0; T < 8; ++T) {
    f32x4 acc = gemm2(wtk, T, c, g, a0, a1);
    int u = 2 * T + (c >> 3);
#pragma unroll
    for (int j = 0; j < 4; ++j) ksp[j] += fS[u][erow + j] * acc[j];
  }
  // W2k: tiles 8..11, col = 128+4u+w (u<16, w<4): u = 4(T-8) + (c>>2)
#pragma unroll
  for (int T = 8; T < 12; ++T) {
    f32x4 acc = gemm2(wtk, T, c, g, a0, a1);
    int u = 4 * (T - 8) + (c >> 2);
#pragma unroll
    for (int j = 0; j < 4; ++j) a2p[j] += fS[u][erow + j] * acc[j];
  }
  // W3k: tiles 12..13, col = 192+4u+w (u<8, w<4): u = 4(T-12) + (c>>2)
#pragma unroll
  for (int T = 12; T < 14; ++T) {
    f32x4 acc = gemm2(wtk, T, c, g, a0, a1);
    int u = 4 * (T - 12) + (c >> 2);
#pragma unroll
    for (int j = 0; j < 4; ++j)
#pragma unroll
      for (int i = 0; i < 3; ++i) a3p[j][i] += fS[16 + u * 3 + i][erow + j] * acc[j];
  }
  // W4k: tiles 14..17, col = 224+8u+w (u<8, w<8): u = 2(T-14) + (c>>3)
#pragma unroll
  for (int T = 14; T < 18; ++T) {
    f32x4 acc = gemm2(wtk, T, c, g, a0, a1);
    int u = 2 * (T - 14) + (c >> 3);
#pragma unroll
    for (int j = 0; j < 4; ++j) ksp[j] += fS[40 + u][erow + j] * acc[j];
  }

  // complete the u-sums across lane splits
  float ksf[4], a2f[4], a3f[4][3];
#pragma unroll
  for (int j = 0; j < 4; ++j) ksf[j] = ksp[j] + __shfl_xor(ksp[j], 8);
#pragma unroll
  for (int j = 0; j < 4; ++j) {
    float v = a2p[j] + __shfl_xor(a2p[j], 4);
    a2f[j] = v + __shfl_xor(v, 8);
  }
#pragma unroll
  for (int j = 0; j < 4; ++j)
#pragma unroll
    for (int i = 0; i < 3; ++i) {
      float v = a3p[j][i] + __shfl_xor(a3p[j][i], 4);
      a3f[j][i] = v + __shfl_xor(v, 8);
    }

  // logit partial per lane, then 16-lane group butterfly
  float lgp[4];
#pragma unroll
  for (int j = 0; j < 4; ++j) {
    float a = 0.f;
    int er = erow + j;
    if (c < 8) {
      a = ksf[j] * qdA[er][c];
    } else if (c < 12) {
      int w = c - 8;
#pragma unroll
      for (int i = 0; i < 3; ++i)
        a += (a2f[j] * y1A[er][i] * FAN_TP + a3f[j][i] * FAN_TP_V) * qvA[er][w * 3 + i];
    }
    lgp[j] = a;
  }
#pragma unroll
  for (int j = 0; j < 4; ++j) {
    lgp[j] += __shfl_xor(lgp[j], 1);
    lgp[j] += __shfl_xor(lgp[j], 2);
    lgp[j] += __shfl_xor(lgp[j], 4);
    lgp[j] += __shfl_xor(lgp[j], 8);
  }
  if (c == 0) {
#pragma unroll
    for (int j = 0; j < 4; ++j) {
      int ee = e0 + erow + j;
      if (ee < E) {
        logit[ee] = lgp[j];
        atomicMaxF(&mx[dstA[erow + j]], lgp[j]);
      }
    }
  }
}

// ---------------- edge kernel 2: exp + denominator ----------------
__global__ void k_edge_ex(const int* __restrict__ dstv, const float* __restrict__ logit,
                          const float* __restrict__ cutb, const float* __restrict__ mx,
                          float* __restrict__ ex, float* __restrict__ z, int E) {
  int e = blockIdx.x * blockDim.x + threadIdx.x;
  if (e >= E) return;
  int t = dstv[e];
  float m = mx[t];
  if (m == -INFINITY) m = 0.f;
  float v = cutb[e] * __expf(logit[e] - m);
  ex[e] = v;
  atomicAdd(&z[t], v);
}

// ---------------- edge kernel 3: V path (MFMA, fused) ----------------
// C[64e][576c] = h @ Wv; wave wv owns M-tile wv, all 36 N-tiles; contraction fused.
__global__ void __launch_bounds__(256)
k_edge_v(const float* __restrict__ pos, const float* __restrict__ x,
         const float* __restrict__ fcv1, const unsigned short* __restrict__ wt,
         const int* __restrict__ srcv, const int* __restrict__ dstv,
         const float* __restrict__ ex, const float* __restrict__ z,
         float* __restrict__ agg, int E) {
  __shared__ alignas(16) unsigned short h_lds[64 * 72];
  __shared__ float fS[48][64];   // fs 0..15 | fv 16..39 | vy 40..47
  __shared__ float y1A[64][4];
  __shared__ float wgtA[64];
  __shared__ int dstA[64];

  const int tid = threadIdx.x;
  const int wv = __builtin_amdgcn_readfirstlane(tid >> 6);
  const int lane = tid & 63;
  const int e0 = blockIdx.x * 64;
  const int eL = e0 + lane;
  const bool valid = eL < E;

  int s = valid ? srcv[eL] : 0, t = valid ? dstv[eL] : 0;

  float y1v[3], d;
  {
    float vx = pos[s * 3 + 0] - pos[t * 3 + 0];
    float vy_ = pos[s * 3 + 1] - pos[t * 3 + 1];
    float vz = pos[s * 3 + 2] - pos[t * 3 + 2];
    d = sqrtf(vx * vx + vy_ * vy_ + vz * vz + 1e-24f);
    float inv = SQ3F / d;
    y1v[0] = vx * inv; y1v[1] = vy_ * inv; y1v[2] = vz * inv;
  }
  float emb[16];
  edge_emb(d, emb);
  float h[16];
  radial_hidden16(fcv1, emb, wv, h);
  {
    unsigned int hw[8];
#pragma unroll
    for (int i = 0; i < 8; ++i)
      hw[i] = (unsigned int)f2bf(h[2 * i]) | ((unsigned int)f2bf(h[2 * i + 1]) << 16);
    uint4 w0 = {hw[0], hw[1], hw[2], hw[3]};
    uint4 w1 = {hw[4], hw[5], hw[6], hw[7]};
    *(uint4*)&h_lds[lane * 72 + 16 * wv] = w0;
    *(uint4*)&h_lds[lane * 72 + 16 * wv + 8] = w1;
  }

  if (wv == 0) {
    const float* xs = x + s * 40;
    float fvl[24];
#pragma unroll
    for (int i = 0; i < 16; ++i) fS[i][lane] = xs[i];
#pragma unroll
    for (int i = 0; i < 24; ++i) { fvl[i] = xs[16 + i]; fS[16 + i][lane] = fvl[i]; }
#pragma unroll
    for (int u = 0; u < 8; ++u)
      fS[40 + u][lane] = (fvl[u * 3] * y1v[0] + fvl[u * 3 + 1] * y1v[1] +
                          fvl[u * 3 + 2] * y1v[2]) * INV_SQ3F;
    y1A[lane][0] = y1v[0]; y1A[lane][1] = y1v[1]; y1A[lane][2] = y1v[2];
    dstA[lane] = t;
    float zz = z[t];
    zz = (zz == 0.f) ? 1.f : zz;
    float alpha = (valid ? ex[eL] : 0.f) / zz;
    wgtA[lane] = sqrtf(alpha + 1e-12f);
  }
  __syncthreads();

  const int c = lane & 15, g = lane >> 4;
  const int erow = 16 * wv + 4 * g;

  bf16x8 a0 = __builtin_bit_cast(bf16x8, *(const uint4*)&h_lds[(16 * wv + c) * 72 + 8 * g]);
  bf16x8 a1 = __builtin_bit_cast(bf16x8, *(const uint4*)&h_lds[(16 * wv + c) * 72 + 32 + 8 * g]);

  float vs[4] = {0.f, 0.f, 0.f, 0.f};
  float b2[4] = {0.f, 0.f, 0.f, 0.f};
  float b3[4][3] = {{0.f}};

  // W1: tiles 0..15, col = 16u+w: u = T, w = c
#pragma unroll
  for (int T = 0; T < 16; ++T) {
    f32x4 acc = gemm2(wt, T, c, g, a0, a1);
#pragma unroll
    for (int j = 0; j < 4; ++j) vs[j] += fS[T][erow + j] * acc[j];
  }
  // W2: tiles 16..23, col = 256+8u+w (u<16, w<8): u = 2(T-16) + (c>>3)
#pragma unroll
  for (int T = 16; T < 24; ++T) {
    f32x4 acc = gemm2(wt, T, c, g, a0, a1);
    int u = 2 * (T - 16) + (c >> 3);
#pragma unroll
    for (int j = 0; j < 4; ++j) b2[j] += fS[u][erow + j] * acc[j];
  }
  // W3: tiles 24..27, col = 384+8u+w (u<8, w<8): u = 2(T-24) + (c>>3)
#pragma unroll
  for (int T = 24; T < 28; ++T) {
    f32x4 acc = gemm2(wt, T, c, g, a0, a1);
    int u = 2 * (T - 24) + (c >> 3);
#pragma unroll
    for (int j = 0; j < 4; ++j)
#pragma unroll
      for (int i = 0; i < 3; ++i) b3[j][i] += fS[16 + u * 3 + i][erow + j] * acc[j];
  }
  // W4: tiles 28..35, col = 448+16u+w: u = T-28, w = c
#pragma unroll
  for (int T = 28; T < 36; ++T) {
    f32x4 acc = gemm2(wt, T, c, g, a0, a1);
#pragma unroll
    for (int j = 0; j < 4; ++j) vs[j] += fS[40 + (T - 28)][erow + j] * acc[j];
  }

#pragma unroll
  for (int j = 0; j < 4; ++j) b2[j] += __shfl_xor(b2[j], 8);
#pragma unroll
  for (int j = 0; j < 4; ++j)
#pragma unroll
    for (int i = 0; i < 3; ++i) b3[j][i] += __shfl_xor(b3[j][i], 8);

  // scatter: lane owns col c of 4 edges
#pragma unroll
  for (int j = 0; j < 4; ++j) {
    int er = erow + j;
    int ee = e0 + er;
    if (ee >= E) continue;
    float w = wgtA[er];
    float* at = agg + dstA[er] * 40;
    atomicAdd(&at[c], w * vs[j] * FAN_TP);
    if (c < 8) {
#pragma unroll
      for (int i = 0; i < 2; ++i) {
        float v = b2[j] * y1A[er][i] * FAN_TP + b3[j][i] * FAN_TP_V;
        atomicAdd(&at[16 + c * 3 + i], w * v);
      }
    } else {
      float v = b2[j] * y1A[er][2] * FAN_TP + b3[j][2] * FAN_TP_V;
      atomicAdd(&at[16 + (c - 8) * 3 + 2], w * v);
    }
  }
}

// ---------------- output kernel ----------------
template <bool BF>
__global__ void k_out(const float* __restrict__ x, const float* __restrict__ rb0,
                      const float* __restrict__ rb1, const float* __restrict__ re0,
                      const float* __restrict__ re1, void* __restrict__ out, int N,
                      const int* __restrict__ flag) {
  if ((*flag != 0) != BF) return;
  int n = blockIdx.x * blockDim.x + threadIdx.x;
  if (n >= N) return;
  float b[20], eta[20];
  lin_apply<8, 4>(x + n * 40, rb0, rb1, b);
  lin_apply<8, 4>(x + n * 40, re0, re1, eta);
  if (BF) {
    __hip_bfloat16* o = (__hip_bfloat16*)out;
#pragma unroll
    for (int j = 0; j < 20; ++j) o[n * 20 + j] = __float2bfloat16(b[j]);
#pragma unroll
    for (int j = 0; j < 20; ++j) o[N * 20 + n * 20 + j] = __float2bfloat16(eta[j]);
  } else {
    float* o = (float*)out;
#pragma unroll
    for (int j = 0; j < 20; ++j) o[n * 20 + j] = b[j];
#pragma unroll
    for (int j = 0; j < 20; ++j) o[N * 20 + n * 20 + j] = eta[j];
  }
}

// ---------------- host ----------------
extern "C" void kernel_launch(void* const* d_in, const int* in_sizes, int n_in,
                              void* d_out, int out_size, void* d_ws, size_t ws_size,
                              hipStream_t stream) {
  float* ws = (float*)d_ws;
  const int N = in_sizes[0] / 40;
  const int E = in_sizes[16];
  const int* src = (const int*)d_in[16];
  const int* dst = (const int*)d_in[17];
  int* flag = (int*)(ws + OFF_FLAG);
  unsigned short* wt = (unsigned short*)(ws + OFF_WT);
  unsigned short* wtk = (unsigned short*)(ws + OFF_WTK);

  k_detect<<<1, 64, 0, stream>>>((const unsigned int*)d_in[0], flag);

  CvtArgs ca;
  const int order[16] = {2, 3, 4, 5, 6, 7, 8, 9, 10, 11, 12, 13, 14, 15, 0, 1};
  const int offs[16] = {OFF_LIN0, OFF_LIN1, OFF_HQ0, OFF_HQ1, OFF_FCK1, OFF_FCK2,
                        OFF_FCV1, OFF_FCV2, OFF_DOT0, OFF_DOT1, OFF_RB0, OFF_RB1,
                        OFF_RE0, OFF_RE1, OFF_F, OFF_POS};
  for (int i = 0; i < 16; ++i) {
    ca.src[i] = d_in[order[i]];
    ca.n[i] = in_sizes[order[i]];
    ca.off[i] = offs[i];
  }
  k_cvt<false><<<512, 256, 0, stream>>>(ca, ws, flag);
  k_cvt<true><<<512, 256, 0, stream>>>(ca, ws, flag);
  k_wt<<<(2 * 576 * 64 + 255) / 256, 256, 0, stream>>>(ws + OFF_FCV2, wt);
  k_wtk<<<(2 * 288 * 64 + 255) / 256, 256, 0, stream>>>(ws + OFF_FCK2, wtk);

  float* x = ws + OFF_X;
  float* q = ws + OFF_Q;
  float* mx = ws + OFF_MX;
  float* z = ws + OFF_Z;
  float* agg = ws + OFF_AGG;
  float* logit = ws + OFF_LOGIT;
  float* cutb = ws + OFF_CUT;
  float* exb = ws + OFF_EX;
  const float* pos = ws + OFF_POS;

  const int nodeBlocks = (N + 255) / 256;
  const int vecBlocks = (N * 40 + 255) / 256;
  const int edgeBlocks = (E + 255) / 256;
  const int eb64 = (E + 63) / 64;   // block = 64 edges

  k_lin_in<<<nodeBlocks, 256, 0, stream>>>(ws + OFF_F, ws + OFF_LIN0, ws + OFF_LIN1, x, N);

  for (int l = 0; l < 2; ++l) {
    k_init<<<vecBlocks, 256, 0, stream>>>(mx, z, agg, N);
    k_q<<<nodeBlocks, 256, 0, stream>>>(x, ws + OFF_HQ0 + l * 128, ws + OFF_HQ1 + l * 32, q, N);
    k_edge_k<<<eb64, 256, 0, stream>>>(
        pos, x, q, ws + OFF_FCK1 + l * 1024, wtk + l * 18432,
        ws + OFF_DOT0 + l * 64, ws + OFF_DOT1 + l * 16, src, dst, logit, cutb, mx, E);
    k_edge_ex<<<edgeBlocks, 256, 0, stream>>>(dst, logit, cutb, mx, exb, z, E);
    k_edge_v<<<eb64, 256, 0, stream>>>(
        pos, x, ws + OFF_FCV1 + l * 1024, wt + l * 36864, src, dst, exb, z, agg, E);
    k_update<<<vecBlocks, 256, 0, stream>>>(x, agg, N * 40);
  }

  k_out<false><<<nodeBlocks, 256, 0, stream>>>(x, ws + OFF_RB0, ws + OFF_RB1,
                                               ws + OFF_RE0, ws + OFF_RE1, d_out, N, flag);
  k_out<true><<<nodeBlocks, 256, 0, stream>>>(x, ws + OFF_RB0, ws + OFF_RB1,
                                              ws + OFF_RE0, ws + OFF_RE1, d_out, N, flag);
}